// Round 1
// baseline (917.762 us; speedup 1.0000x reference)
//
#include <hip/hip_runtime.h>
#include <cstdint>
#include <cstddef>

#define B_     128
#define N_TOK  196
#define D_IN   768
#define K_SEL  144
#define P_     2000
#define C_     192
#define NC_    200
#define TPB    145            // tokens per batch: 1 cls + 144 selected
#define M_TOT  (B_ * TPB)     // 18560 = 290 * 64
#define EPS_   1e-4f

// ---------------------------------------------------------------------------
// Kernel 1: per-batch top-K (stable, lower-index-wins ties like lax.top_k),
// writes absolute x_tokens row indices: [cls, 1+idx0, 1+idx1, ...] ascending.
// ---------------------------------------------------------------------------
__global__ __launch_bounds__(256) void topk_rowidx(const float* __restrict__ attn,
                                                   int* __restrict__ rowidx) {
  __shared__ float av[N_TOK];
  __shared__ int   flag[N_TOK];
  int b = blockIdx.x;
  int t = threadIdx.x;
  if (t < N_TOK) av[t] = attn[b * N_TOK + t];
  __syncthreads();
  if (t < N_TOK) {
    float v = av[t];
    int rank = 0;
    for (int j = 0; j < N_TOK; ++j) {
      float u = av[j];
      rank += (u > v || (u == v && j < t)) ? 1 : 0;
    }
    flag[t] = (rank < K_SEL) ? 1 : 0;
  }
  __syncthreads();
  if (t == 0) rowidx[b * TPB] = b * (N_TOK + 1);  // cls row
  if (t < N_TOK && flag[t]) {
    int pos = 0;
    for (int j = 0; j < t; ++j) pos += flag[j];
    rowidx[b * TPB + 1 + pos] = b * (N_TOK + 1) + 1 + t;
  }
}

// ---------------------------------------------------------------------------
// Tiled fp32 GEMM: out[M,N] = act(A[M,K] @ W[N,K]^T + b). BM=BN=64, BK=16,
// 4x4 per thread, 256 threads. GATHER: A row index via rowidx (layer 1).
// ACT: 0 = relu, 1 = sigmoid.
// ---------------------------------------------------------------------------
template <int ACT, bool GATHER>
__global__ __launch_bounds__(256) void mlp_gemm(
    const float* __restrict__ A, const int* __restrict__ rowidx, int lda,
    const float* __restrict__ W, const float* __restrict__ bias,
    float* __restrict__ out, int N, int Kd) {
  __shared__ __align__(16) float As[16][68];
  __shared__ __align__(16) float Ws[16][68];
  int bm = blockIdx.x * 64, bn = blockIdx.y * 64;
  int tid = threadIdx.x;
  int tx = tid & 15, ty = tid >> 4;
  int lk = tid & 15, lr = tid >> 4;
  float acc[4][4] = {};
  for (int k0 = 0; k0 < Kd; k0 += 16) {
#pragma unroll
    for (int i = 0; i < 4; ++i) {
      int r = lr + i * 16;
      size_t arow = GATHER ? (size_t)rowidx[bm + r] : (size_t)(bm + r);
      As[lk][r] = A[arow * (size_t)lda + k0 + lk];
    }
#pragma unroll
    for (int i = 0; i < 4; ++i) {
      int r = lr + i * 16;
      Ws[lk][r] = W[(size_t)(bn + r) * Kd + k0 + lk];
    }
    __syncthreads();
#pragma unroll
    for (int kk = 0; kk < 16; ++kk) {
      float4 a4 = *reinterpret_cast<const float4*>(&As[kk][ty * 4]);
      float4 b4 = *reinterpret_cast<const float4*>(&Ws[kk][tx * 4]);
      float av[4] = {a4.x, a4.y, a4.z, a4.w};
      float bv[4] = {b4.x, b4.y, b4.z, b4.w};
#pragma unroll
      for (int i = 0; i < 4; ++i)
#pragma unroll
        for (int j = 0; j < 4; ++j) acc[i][j] += av[i] * bv[j];
    }
    __syncthreads();
  }
#pragma unroll
  for (int i = 0; i < 4; ++i) {
    int row = bm + ty * 4 + i;
#pragma unroll
    for (int j = 0; j < 4; ++j) {
      int col = bn + tx * 4 + j;
      float v = acc[i][j] + bias[col];
      v = (ACT == 0) ? fmaxf(v, 0.0f) : 1.0f / (1.0f + expf(-v));
      out[(size_t)row * N + col] = v;
    }
  }
}

// ---------------------------------------------------------------------------
// fnorm[m] = sum_k F[m][k]^2. One wave per row.
// ---------------------------------------------------------------------------
__global__ __launch_bounds__(256) void fnorm_k(const float* __restrict__ F,
                                               float* __restrict__ fnorm) {
  int m = blockIdx.x * 4 + (threadIdx.x >> 6);
  int lane = threadIdx.x & 63;
  const float* f = F + (size_t)m * C_;
  float s = 0.f;
  for (int k = lane; k < C_; k += 64) s += f[k] * f[k];
  for (int o = 32; o > 0; o >>= 1) s += __shfl_down(s, o, 64);
  if (lane == 0) fnorm[m] = s;
}

// pnorm for both proto arrays: rows 0..1999 local, 2000..3999 global
__global__ __launch_bounds__(256) void pnorm_k(const float* __restrict__ pl,
                                               const float* __restrict__ pg,
                                               float* __restrict__ pnl,
                                               float* __restrict__ png) {
  int m = blockIdx.x * 4 + (threadIdx.x >> 6);
  int lane = threadIdx.x & 63;
  const float* src = (m < P_) ? (pl + (size_t)m * C_) : (pg + (size_t)(m - P_) * C_);
  float s = 0.f;
  for (int k = lane; k < C_; k += 64) s += src[k] * src[k];
  for (int o = 32; o > 0; o >>= 1) s += __shfl_down(s, o, 64);
  if (lane == 0) {
    if (m < P_) pnl[m] = s; else png[m - P_] = s;
  }
}

// ---------------------------------------------------------------------------
// Image-token distances: for each (batch, proto) min over 144 tokens of
// relu(|f|^2 - 2 f.p + |p|^2), then act = log((d+1)/(d+eps)).
// Block: 128 protos x (3 chunks of 48 tokens), 256 threads (tx:8 protos, ty:3 toks)
// ---------------------------------------------------------------------------
__global__ __launch_bounds__(256) void dist_img(
    const float* __restrict__ F, const float* __restrict__ proto,
    const float* __restrict__ fnorm, const float* __restrict__ pnorm,
    float* __restrict__ act_l) {
  __shared__ __align__(16) float Fs[16][49];
  __shared__ __align__(16) float Ps[16][132];
  __shared__ float red[16][128];
  int b = blockIdx.y;
  int p0 = blockIdx.x * 128;
  int tid = threadIdx.x;
  int tx = tid & 15, ty = tid >> 4;
  int lk = tid & 15, lr = tid >> 4;
  float minv[8];
#pragma unroll
  for (int j = 0; j < 8; ++j) minv[j] = 3.4e38f;

  for (int chunk = 0; chunk < 3; ++chunk) {
    float acc[3][8] = {};
    int rowbase = b * TPB + 1 + chunk * 48;
    for (int k0 = 0; k0 < C_; k0 += 16) {
#pragma unroll
      for (int i = 0; i < 3; ++i) {
        int r = lr + i * 16;
        Fs[lk][r] = F[(size_t)(rowbase + r) * C_ + k0 + lk];
      }
#pragma unroll
      for (int i = 0; i < 8; ++i) {
        int r = lr + i * 16;
        int p = p0 + r;
        Ps[lk][r] = (p < P_) ? proto[(size_t)p * C_ + k0 + lk] : 0.0f;
      }
      __syncthreads();
#pragma unroll
      for (int kk = 0; kk < 16; ++kk) {
        float a0 = Fs[kk][ty * 3 + 0];
        float a1 = Fs[kk][ty * 3 + 1];
        float a2 = Fs[kk][ty * 3 + 2];
        float4 q0 = *reinterpret_cast<const float4*>(&Ps[kk][tx * 8]);
        float4 q1 = *reinterpret_cast<const float4*>(&Ps[kk][tx * 8 + 4]);
        float bb[8] = {q0.x, q0.y, q0.z, q0.w, q1.x, q1.y, q1.z, q1.w};
#pragma unroll
        for (int j = 0; j < 8; ++j) {
          acc[0][j] += a0 * bb[j];
          acc[1][j] += a1 * bb[j];
          acc[2][j] += a2 * bb[j];
        }
      }
      __syncthreads();
    }
#pragma unroll
    for (int i = 0; i < 3; ++i) {
      float fn = fnorm[rowbase + ty * 3 + i];
#pragma unroll
      for (int j = 0; j < 8; ++j) {
        int p = p0 + tx * 8 + j;
        float pn = (p < P_) ? pnorm[p] : 0.0f;
        float d = fmaxf(fn - 2.0f * acc[i][j] + pn, 0.0f);
        minv[j] = fminf(minv[j], d);
      }
    }
  }
#pragma unroll
  for (int j = 0; j < 8; ++j) red[ty][tx * 8 + j] = minv[j];
  __syncthreads();
  for (int s = 8; s > 0; s >>= 1) {
    if (ty < s) {
#pragma unroll
      for (int j = 0; j < 8; ++j) {
        int c = tx * 8 + j;
        red[ty][c] = fminf(red[ty][c], red[ty + s][c]);
      }
    }
    __syncthreads();
  }
  if (ty == 0) {
#pragma unroll
    for (int j = 0; j < 8; ++j) {
      int p = p0 + tx * 8 + j;
      if (p < P_) {
        float d = red[0][tx * 8 + j];
        act_l[(size_t)b * P_ + p] = logf((d + 1.0f) / (d + EPS_));
      }
    }
  }
}

// ---------------------------------------------------------------------------
// CLS distances: one thread per (b, p). act_g[b][p] = log((d+1)/(d+eps)).
// ---------------------------------------------------------------------------
__global__ __launch_bounds__(256) void dist_cls(
    const float* __restrict__ F, const float* __restrict__ proto,
    const float* __restrict__ fnorm, const float* __restrict__ pnorm,
    float* __restrict__ act_g) {
  int i = blockIdx.x * 256 + threadIdx.x;  // exactly 128*2000 threads
  int b = i / P_, p = i - b * P_;
  const float* f  = F + (size_t)(b * TPB) * C_;
  const float* pr = proto + (size_t)p * C_;
  float dot = 0.f;
  for (int k = 0; k < C_; k += 4) {
    float4 fv = *reinterpret_cast<const float4*>(f + k);
    float4 pv = *reinterpret_cast<const float4*>(pr + k);
    dot += fv.x * pv.x + fv.y * pv.y + fv.z * pv.z + fv.w * pv.w;
  }
  float d = fmaxf(fnorm[b * TPB] - 2.f * dot + pnorm[p], 0.f);
  act_g[i] = logf((d + 1.0f) / (d + EPS_));
}

// ---------------------------------------------------------------------------
// Final: logits[b][c] = 0.3 * act_g[b].lwg[c] + 0.7 * act_l[b].lw[c]
// ---------------------------------------------------------------------------
__global__ __launch_bounds__(256) void final_k(
    const float* __restrict__ act_g, const float* __restrict__ act_l,
    const float* __restrict__ lwg, const float* __restrict__ lw,
    float* __restrict__ out) {
  __shared__ __align__(16) float ag[P_];
  __shared__ __align__(16) float al[P_];
  int b = blockIdx.x;
  for (int i = threadIdx.x; i < P_; i += 256) {
    ag[i] = act_g[(size_t)b * P_ + i];
    al[i] = act_l[(size_t)b * P_ + i];
  }
  __syncthreads();
  int c = threadIdx.x;
  if (c < NC_) {
    const float* wg = lwg + (size_t)c * P_;
    const float* wl = lw + (size_t)c * P_;
    float s0 = 0.f, s1 = 0.f;
    for (int k = 0; k < P_; k += 4) {
      float4 g4 = *reinterpret_cast<const float4*>(&ag[k]);
      float4 l4 = *reinterpret_cast<const float4*>(&al[k]);
      float4 wg4 = *reinterpret_cast<const float4*>(wg + k);
      float4 wl4 = *reinterpret_cast<const float4*>(wl + k);
      s0 += g4.x * wg4.x + g4.y * wg4.y + g4.z * wg4.z + g4.w * wg4.w;
      s1 += l4.x * wl4.x + l4.y * wl4.y + l4.z * wl4.z + l4.w * wl4.w;
    }
    out[(size_t)b * NC_ + c] = 0.3f * s0 + 0.7f * s1;
  }
}

// ---------------------------------------------------------------------------
extern "C" void kernel_launch(void* const* d_in, const int* in_sizes, int n_in,
                              void* d_out, int out_size, void* d_ws, size_t ws_size,
                              hipStream_t stream) {
  const float* x_tokens = (const float*)d_in[0];
  const float* attn     = (const float*)d_in[1];
  const float* w1 = (const float*)d_in[2];
  const float* b1 = (const float*)d_in[3];
  const float* w2 = (const float*)d_in[4];
  const float* b2 = (const float*)d_in[5];
  const float* w3 = (const float*)d_in[6];
  const float* b3 = (const float*)d_in[7];
  const float* w4 = (const float*)d_in[8];
  const float* b4 = (const float*)d_in[9];
  const float* proto_l = (const float*)d_in[10];
  const float* proto_g = (const float*)d_in[11];
  const float* last_w  = (const float*)d_in[12];
  const float* last_wg = (const float*)d_in[13];
  float* out = (float*)d_out;

  // workspace carve (~59.3 MB)
  char* wsb = (char*)d_ws;
  auto alloc = [&](size_t bytes) {
    char* p = wsb;
    wsb += (bytes + 255) & ~(size_t)255;
    return p;
  };
  int*   rowidx = (int*)  alloc((size_t)M_TOT * sizeof(int));
  float* fnorm  = (float*)alloc((size_t)M_TOT * sizeof(float));
  float* pnl    = (float*)alloc((size_t)P_ * sizeof(float));
  float* png    = (float*)alloc((size_t)P_ * sizeof(float));
  float* actg   = (float*)alloc((size_t)B_ * P_ * sizeof(float));
  float* actl   = (float*)alloc((size_t)B_ * P_ * sizeof(float));
  float* buf1   = (float*)alloc((size_t)M_TOT * 384 * sizeof(float));
  float* buf2   = (float*)alloc((size_t)M_TOT * 384 * sizeof(float));

  topk_rowidx<<<B_, 256, 0, stream>>>(attn, rowidx);

  // L1: gather(x_tokens) [M,768] @ w1^T -> relu -> buf1 [M,384]
  mlp_gemm<0, true><<<dim3(M_TOT / 64, 384 / 64), 256, 0, stream>>>(
      x_tokens, rowidx, D_IN, w1, b1, buf1, 384, 768);
  // L2: buf1 @ w2^T -> relu -> buf2 [M,384]
  mlp_gemm<0, false><<<dim3(M_TOT / 64, 384 / 64), 256, 0, stream>>>(
      buf1, nullptr, 384, w2, b2, buf2, 384, 384);
  // L3: buf2 @ w3^T -> relu -> buf1 [M,192]
  mlp_gemm<0, false><<<dim3(M_TOT / 64, 192 / 64), 256, 0, stream>>>(
      buf2, nullptr, 384, w3, b3, buf1, 192, 384);
  // L4: buf1 @ w4^T -> sigmoid -> buf2 = F [M,192]
  mlp_gemm<1, false><<<dim3(M_TOT / 64, 192 / 64), 256, 0, stream>>>(
      buf1, nullptr, 192, w4, b4, buf2, 192, 192);

  fnorm_k<<<M_TOT / 4, 256, 0, stream>>>(buf2, fnorm);
  pnorm_k<<<(2 * P_) / 4, 256, 0, stream>>>(proto_l, proto_g, pnl, png);

  dist_img<<<dim3((P_ + 127) / 128, B_), 256, 0, stream>>>(buf2, proto_l, fnorm, pnl, actl);
  dist_cls<<<(B_ * P_) / 256, 256, 0, stream>>>(buf2, proto_g, fnorm, png, actg);

  final_k<<<B_, 256, 0, stream>>>(actg, actl, last_wg, last_w, out);
}

// Round 2
// 241.937 us; speedup vs baseline: 3.7934x; 3.7934x over previous
//
#include <hip/hip_runtime.h>
#include <cstdint>
#include <cstddef>

#define B_     128
#define N_TOK  196
#define D_IN   768
#define K_SEL  144
#define P_     2000
#define PPAD   2048
#define C_     192
#define NC_    200
#define RPB    160            // padded rows per batch: 1 cls + 144 sel + 15 pad
#define M_PAD  (B_ * RPB)     // 20480
#define EPS_   1e-4f

typedef __bf16 bf16;
typedef bf16 bf16x8 __attribute__((ext_vector_type(8)));
typedef bf16 bf16x4 __attribute__((ext_vector_type(4)));
typedef float f32x4 __attribute__((ext_vector_type(4)));

#define MFMA(a, b, c) __builtin_amdgcn_mfma_f32_16x16x32_bf16(a, b, c, 0, 0, 0)

__device__ __forceinline__ void gload_lds16(const void* g, void* l) {
  __builtin_amdgcn_global_load_lds(
      (const __attribute__((address_space(1))) unsigned int*)g,
      (__attribute__((address_space(3))) unsigned int*)l, 16, 0, 0);
}

// ---------------------------------------------------------------------------
// top-K (stable, lower-index-wins like lax.top_k) -> absolute x_tokens row per
// padded slot: slot 0 = cls, 1..144 = sorted selected, 145..159 = -1.
// ---------------------------------------------------------------------------
__global__ __launch_bounds__(256) void topk_rowidx(const float* __restrict__ attn,
                                                   int* __restrict__ rowidx) {
  __shared__ float av[N_TOK];
  __shared__ int   flag[N_TOK];
  int b = blockIdx.x, t = threadIdx.x;
  if (t < N_TOK) av[t] = attn[b * N_TOK + t];
  __syncthreads();
  if (t < N_TOK) {
    float v = av[t];
    int rank = 0;
    for (int j = 0; j < N_TOK; ++j) {
      float u = av[j];
      rank += (u > v || (u == v && j < t)) ? 1 : 0;
    }
    flag[t] = (rank < K_SEL) ? 1 : 0;
  }
  __syncthreads();
  if (t == 0) rowidx[b * RPB] = b * (N_TOK + 1);
  if (t < RPB - (K_SEL + 1)) rowidx[b * RPB + K_SEL + 1 + t] = -1;
  if (t < N_TOK && flag[t]) {
    int pos = 0;
    for (int j = 0; j < t; ++j) pos += flag[j];
    rowidx[b * RPB + 1 + pos] = b * (N_TOK + 1) + 1 + t;
  }
}

// ---------------------------------------------------------------------------
// f32 -> bf16 convert with zero-padding of the tail (n_valid..n_total).
// ---------------------------------------------------------------------------
__global__ __launch_bounds__(256) void cvt_pad(const float* __restrict__ s,
                                               bf16* __restrict__ d,
                                               int n_valid, int n_total) {
  int i = (blockIdx.x * 256 + threadIdx.x) * 4;
  if (i >= n_total) return;
  bf16x4 o;
#pragma unroll
  for (int j = 0; j < 4; ++j)
    o[j] = (i + j < n_valid) ? (bf16)s[i + j] : (bf16)0.f;
  *reinterpret_cast<bf16x4*>(d + i) = o;
}

// ---------------------------------------------------------------------------
// Gather selected token rows from x_tokens, convert f32 -> bf16.
// One block per padded row, 192 threads * float4.
// ---------------------------------------------------------------------------
__global__ __launch_bounds__(192) void gather_cvt(const float* __restrict__ x,
                                                  const int* __restrict__ rowidx,
                                                  bf16* __restrict__ A0) {
  int row = blockIdx.x;
  int src = rowidx[row];
  int t = threadIdx.x;
  bf16x4 o;
  if (src >= 0) {
    float4 v = *reinterpret_cast<const float4*>(x + (size_t)src * D_IN + t * 4);
    o[0] = (bf16)v.x; o[1] = (bf16)v.y; o[2] = (bf16)v.z; o[3] = (bf16)v.w;
  } else {
    o[0] = (bf16)0.f; o[1] = (bf16)0.f; o[2] = (bf16)0.f; o[3] = (bf16)0.f;
  }
  *reinterpret_cast<bf16x4*>(A0 + (size_t)row * D_IN + t * 4) = o;
}

// ---------------------------------------------------------------------------
// bf16 MFMA GEMM: out[M_PAD,N] = act(A[M_PAD,Kd] @ W[N,Kd]^T + bias), bf16 out.
// BM=128 BN=64 BK=64, 4 waves (2x2), wave tile 64x32 (4x2 frags of 16x16x32).
// LDS XOR-swizzled (16B granule, byte ^= (row&7)<<4) with pre-swizzled global
// source so global_load_lds stays linear-dest (rule #21).
// ACT: 0 relu, 1 sigmoid.
// ---------------------------------------------------------------------------
template <int ACT>
__global__ __launch_bounds__(256, 2) void gemm_bf16(
    const bf16* __restrict__ A, const bf16* __restrict__ W,
    const float* __restrict__ bias, bf16* __restrict__ out, int N, int Kd) {
  __shared__ __align__(16) bf16 As[128 * 64];
  __shared__ __align__(16) bf16 Bs[64 * 64];
  const int bm = blockIdx.x * 128, bn = blockIdx.y * 64;
  const int tid = threadIdx.x;
  const int lane = tid & 63, wid = tid >> 6;
  const int wm = (wid >> 1) * 64, wn = (wid & 1) * 32;
  const int l15 = lane & 15, lhi = lane >> 4;
  f32x4 acc[4][2] = {};
  for (int k0 = 0; k0 < Kd; k0 += 64) {
#pragma unroll
    for (int i = 0; i < 4; ++i) {
      int o = i * 256 + tid;
      int r = o >> 3, cb = o & 7;
      int gc = (cb ^ (r & 7)) * 8;
      gload_lds16(A + (size_t)(bm + r) * Kd + k0 + gc, (char*)As + o * 16);
    }
#pragma unroll
    for (int i = 0; i < 2; ++i) {
      int o = i * 256 + tid;
      int r = o >> 3, cb = o & 7;
      int gc = (cb ^ (r & 7)) * 8;
      gload_lds16(W + (size_t)(bn + r) * Kd + k0 + gc, (char*)Bs + o * 16);
    }
    __syncthreads();
#pragma unroll
    for (int kk = 0; kk < 2; ++kk) {
      bf16x8 bfr[2];
#pragma unroll
      for (int nf = 0; nf < 2; ++nf) {
        int rr = wn + nf * 16 + l15;
        int c = kk * 4 + lhi;
        bfr[nf] = *reinterpret_cast<const bf16x8*>(
            (const char*)Bs + (rr * 8 + (c ^ (rr & 7))) * 16);
      }
#pragma unroll
      for (int mf = 0; mf < 4; ++mf) {
        int rr = wm + mf * 16 + l15;
        int c = kk * 4 + lhi;
        bf16x8 afr = *reinterpret_cast<const bf16x8*>(
            (const char*)As + (rr * 8 + (c ^ (rr & 7))) * 16);
#pragma unroll
        for (int nf = 0; nf < 2; ++nf)
          acc[mf][nf] = MFMA(afr, bfr[nf], acc[mf][nf]);
      }
    }
    __syncthreads();
  }
#pragma unroll
  for (int mf = 0; mf < 4; ++mf)
#pragma unroll
    for (int nf = 0; nf < 2; ++nf) {
      int col = bn + wn + nf * 16 + l15;
      float bv = bias[col];
#pragma unroll
      for (int q = 0; q < 4; ++q) {
        int row = bm + wm + mf * 16 + lhi * 4 + q;
        float v = acc[mf][nf][q] + bv;
        v = (ACT == 0) ? fmaxf(v, 0.f) : 1.f / (1.f + expf(-v));
        out[(size_t)row * N + col] = (bf16)v;
      }
    }
}

// ---------------------------------------------------------------------------
// fnorm[m] = sum_k F_bf16[m][k]^2 (f32 accum).
// ---------------------------------------------------------------------------
__global__ __launch_bounds__(256) void fnorm_bf(const bf16* __restrict__ F,
                                                float* __restrict__ fnorm) {
  int m = blockIdx.x * 4 + (threadIdx.x >> 6);
  int lane = threadIdx.x & 63;
  const bf16* f = F + (size_t)m * C_;
  float s = 0.f;
#pragma unroll
  for (int k = 0; k < 3; ++k) {
    float v = (float)f[lane + k * 64];
    s += v * v;
  }
  for (int o = 32; o > 0; o >>= 1) s += __shfl_down(s, o, 64);
  if (lane == 0) fnorm[m] = s;
}

__global__ __launch_bounds__(256) void pnorm_bf(const bf16* __restrict__ P,
                                                float* __restrict__ pn) {
  int m = blockIdx.x * 4 + (threadIdx.x >> 6);
  int lane = threadIdx.x & 63;
  const bf16* f = P + (size_t)m * C_;
  float s = 0.f;
#pragma unroll
  for (int k = 0; k < 3; ++k) {
    float v = (float)f[lane + k * 64];
    s += v * v;
  }
  for (int o = 32; o > 0; o >>= 1) s += __shfl_down(s, o, 64);
  if (lane == 0) pn[m] = s;
}

__global__ __launch_bounds__(256) void pnorm_f32(const float* __restrict__ P,
                                                 float* __restrict__ pn) {
  int m = blockIdx.x * 4 + (threadIdx.x >> 6);
  int lane = threadIdx.x & 63;
  const float* f = P + (size_t)m * C_;
  float s = 0.f;
#pragma unroll
  for (int k = 0; k < 3; ++k) {
    float v = f[lane + k * 64];
    s += v * v;
  }
  for (int o = 32; o > 0; o >>= 1) s += __shfl_down(s, o, 64);
  if (lane == 0) pn[m] = s;
}

// ---------------------------------------------------------------------------
// Per-batch distance + min-over-tokens + log activation, bf16 MFMA.
// Block: 160 tokens x 128 protos, K=192 (3 steps of 64). 4 waves, each wave
// all 160 rows x 32 protos (10x2 frags). min d => max a (monotone).
// ---------------------------------------------------------------------------
__global__ __launch_bounds__(256, 2) void dist_img_mfma(
    const bf16* __restrict__ F, const bf16* __restrict__ P,
    const float* __restrict__ fnorm, const float* __restrict__ pnorm,
    float* __restrict__ act_l) {
  __shared__ __align__(16) bf16 Fs[160 * 64];
  __shared__ __align__(16) bf16 Ps[128 * 64];
  __shared__ float fn[RPB];
  const int b = blockIdx.y;
  const int p0 = blockIdx.x * 128;
  const int tid = threadIdx.x;
  const int lane = tid & 63, wid = tid >> 6;
  const int wn = wid * 32;
  const int l15 = lane & 15, lhi = lane >> 4;
  if (tid < RPB) fn[tid] = fnorm[b * RPB + tid];
  f32x4 acc[10][2] = {};
  for (int k0 = 0; k0 < C_; k0 += 64) {
#pragma unroll
    for (int i = 0; i < 5; ++i) {
      int o = i * 256 + tid;
      int r = o >> 3, cb = o & 7;
      int gc = (cb ^ (r & 7)) * 8;
      gload_lds16(F + (size_t)(b * RPB + r) * C_ + k0 + gc, (char*)Fs + o * 16);
    }
#pragma unroll
    for (int i = 0; i < 4; ++i) {
      int o = i * 256 + tid;
      int r = o >> 3, cb = o & 7;
      int gc = (cb ^ (r & 7)) * 8;
      gload_lds16(P + (size_t)(p0 + r) * C_ + k0 + gc, (char*)Ps + o * 16);
    }
    __syncthreads();
#pragma unroll
    for (int kk = 0; kk < 2; ++kk) {
      bf16x8 bfr[2];
#pragma unroll
      for (int nf = 0; nf < 2; ++nf) {
        int rr = wn + nf * 16 + l15;
        int c = kk * 4 + lhi;
        bfr[nf] = *reinterpret_cast<const bf16x8*>(
            (const char*)Ps + (rr * 8 + (c ^ (rr & 7))) * 16);
      }
#pragma unroll
      for (int mf = 0; mf < 10; ++mf) {
        int rr = mf * 16 + l15;
        int c = kk * 4 + lhi;
        bf16x8 afr = *reinterpret_cast<const bf16x8*>(
            (const char*)Fs + (rr * 8 + (c ^ (rr & 7))) * 16);
#pragma unroll
        for (int nf = 0; nf < 2; ++nf)
          acc[mf][nf] = MFMA(afr, bfr[nf], acc[mf][nf]);
      }
    }
    __syncthreads();
  }
#pragma unroll
  for (int nf = 0; nf < 2; ++nf) {
    float mn = 3.4e38f;
#pragma unroll
    for (int mf = 0; mf < 10; ++mf)
#pragma unroll
      for (int q = 0; q < 4; ++q) {
        int row = mf * 16 + lhi * 4 + q;
        float e = fn[row] - 2.f * acc[mf][nf][q];
        if (row >= 1 && row <= K_SEL) mn = fminf(mn, e);
      }
    mn = fminf(mn, __shfl_xor(mn, 16, 64));
    mn = fminf(mn, __shfl_xor(mn, 32, 64));
    int p = p0 + wn + nf * 16 + l15;
    if (lhi == 0 && p < P_) {
      float d = fmaxf(mn + pnorm[p], 0.f);
      act_l[(size_t)b * P_ + p] = logf((d + 1.f) / (d + EPS_));
    }
  }
}

// ---------------------------------------------------------------------------
// CLS distances vs proto_global (f32 protos, bf16 cls feature rows).
// ---------------------------------------------------------------------------
__global__ __launch_bounds__(256) void dist_cls(
    const bf16* __restrict__ F, const float* __restrict__ proto,
    const float* __restrict__ fnorm, const float* __restrict__ pnorm,
    float* __restrict__ act_g) {
  int i = blockIdx.x * 256 + threadIdx.x;  // 128*2000 threads exactly
  int b = i / P_, p = i - b * P_;
  const bf16* f = F + (size_t)(b * RPB) * C_;
  const float* pr = proto + (size_t)p * C_;
  float dot = 0.f;
  for (int k = 0; k < C_; k += 8) {
    bf16x8 fv = *reinterpret_cast<const bf16x8*>(f + k);
    float4 p0 = *reinterpret_cast<const float4*>(pr + k);
    float4 p1 = *reinterpret_cast<const float4*>(pr + k + 4);
    dot += (float)fv[0] * p0.x + (float)fv[1] * p0.y + (float)fv[2] * p0.z +
           (float)fv[3] * p0.w + (float)fv[4] * p1.x + (float)fv[5] * p1.y +
           (float)fv[6] * p1.z + (float)fv[7] * p1.w;
  }
  float d = fmaxf(fnorm[b * RPB] - 2.f * dot + pnorm[p], 0.f);
  act_g[i] = logf((d + 1.f) / (d + EPS_));
}

// ---------------------------------------------------------------------------
// logits[b][c] = 0.3 * act_g[b].lwg[c] + 0.7 * act_l[b].lw[c]
// ---------------------------------------------------------------------------
__global__ __launch_bounds__(256) void final_k(
    const float* __restrict__ act_g, const float* __restrict__ act_l,
    const float* __restrict__ lwg, const float* __restrict__ lw,
    float* __restrict__ out) {
  __shared__ __align__(16) float ag[P_];
  __shared__ __align__(16) float al[P_];
  int b = blockIdx.x;
  for (int i = threadIdx.x; i < P_; i += 256) {
    ag[i] = act_g[(size_t)b * P_ + i];
    al[i] = act_l[(size_t)b * P_ + i];
  }
  __syncthreads();
  int c = threadIdx.x;
  if (c < NC_) {
    const float* wg = lwg + (size_t)c * P_;
    const float* wl = lw + (size_t)c * P_;
    float s0 = 0.f, s1 = 0.f;
    for (int k = 0; k < P_; k += 4) {
      float4 g4 = *reinterpret_cast<const float4*>(&ag[k]);
      float4 l4 = *reinterpret_cast<const float4*>(&al[k]);
      float4 wg4 = *reinterpret_cast<const float4*>(wg + k);
      float4 wl4 = *reinterpret_cast<const float4*>(wl + k);
      s0 += g4.x * wg4.x + g4.y * wg4.y + g4.z * wg4.z + g4.w * wg4.w;
      s1 += l4.x * wl4.x + l4.y * wl4.y + l4.z * wl4.z + l4.w * wl4.w;
    }
    out[(size_t)b * NC_ + c] = 0.3f * s0 + 0.7f * s1;
  }
}

// ---------------------------------------------------------------------------
extern "C" void kernel_launch(void* const* d_in, const int* in_sizes, int n_in,
                              void* d_out, int out_size, void* d_ws, size_t ws_size,
                              hipStream_t stream) {
  const float* x_tokens = (const float*)d_in[0];
  const float* attn     = (const float*)d_in[1];
  const float* w1 = (const float*)d_in[2];
  const float* b1 = (const float*)d_in[3];
  const float* w2 = (const float*)d_in[4];
  const float* b2 = (const float*)d_in[5];
  const float* w3 = (const float*)d_in[6];
  const float* b3 = (const float*)d_in[7];
  const float* w4 = (const float*)d_in[8];
  const float* b4 = (const float*)d_in[9];
  const float* proto_l = (const float*)d_in[10];
  const float* proto_g = (const float*)d_in[11];
  const float* last_w  = (const float*)d_in[12];
  const float* last_wg = (const float*)d_in[13];
  float* out = (float*)d_out;

  char* wsb = (char*)d_ws;
  auto alloc = [&](size_t bytes) {
    char* p = wsb;
    wsb += (bytes + 255) & ~(size_t)255;
    return p;
  };
  // X: A0 (20480x768 bf16) -> later H2 (20480x384) -> later F (20480x192)
  bf16* X = (bf16*)alloc((size_t)M_PAD * D_IN * sizeof(bf16));   // 31.5 MB
  // Y: H1 (20480x384) -> later H3 (20480x192)
  bf16* Y = (bf16*)alloc((size_t)M_PAD * 384 * sizeof(bf16));    // 15.7 MB
  bf16* w1b = (bf16*)alloc((size_t)384 * 768 * sizeof(bf16));
  bf16* w2b = (bf16*)alloc((size_t)384 * 384 * sizeof(bf16));
  bf16* w3b = (bf16*)alloc((size_t)192 * 384 * sizeof(bf16));
  bf16* w4b = (bf16*)alloc((size_t)192 * 192 * sizeof(bf16));
  bf16* plb = (bf16*)alloc((size_t)PPAD * C_ * sizeof(bf16));
  int*   rowidx = (int*)  alloc((size_t)M_PAD * sizeof(int));
  float* fnorm  = (float*)alloc((size_t)M_PAD * sizeof(float));
  float* pnl    = (float*)alloc((size_t)PPAD * sizeof(float));
  float* png    = (float*)alloc((size_t)P_ * sizeof(float));
  float* actg   = (float*)alloc((size_t)B_ * P_ * sizeof(float));
  float* actl   = (float*)alloc((size_t)B_ * P_ * sizeof(float));

  bf16* A0 = X;        // [M_PAD][768]
  bf16* H1 = Y;        // [M_PAD][384]
  bf16* H2 = X;        // [M_PAD][384]
  bf16* H3 = Y;        // [M_PAD][192]
  bf16* Fb = X;        // [M_PAD][192]

  topk_rowidx<<<B_, 256, 0, stream>>>(attn, rowidx);

  cvt_pad<<<(384 * 768 / 4 + 255) / 256, 256, 0, stream>>>(w1, w1b, 384 * 768, 384 * 768);
  cvt_pad<<<(384 * 384 / 4 + 255) / 256, 256, 0, stream>>>(w2, w2b, 384 * 384, 384 * 384);
  cvt_pad<<<(192 * 384 / 4 + 255) / 256, 256, 0, stream>>>(w3, w3b, 192 * 384, 192 * 384);
  cvt_pad<<<(192 * 192 / 4 + 255) / 256, 256, 0, stream>>>(w4, w4b, 192 * 192, 192 * 192);
  cvt_pad<<<(PPAD * C_ / 4 + 255) / 256, 256, 0, stream>>>(proto_l, plb, P_ * C_, PPAD * C_);

  gather_cvt<<<M_PAD, 192, 0, stream>>>(x_tokens, rowidx, A0);

  gemm_bf16<0><<<dim3(M_PAD / 128, 384 / 64), 256, 0, stream>>>(A0, w1b, b1, H1, 384, 768);
  gemm_bf16<0><<<dim3(M_PAD / 128, 384 / 64), 256, 0, stream>>>(H1, w2b, b2, H2, 384, 384);
  gemm_bf16<0><<<dim3(M_PAD / 128, 192 / 64), 256, 0, stream>>>(H2, w3b, b3, H3, 192, 384);
  gemm_bf16<1><<<dim3(M_PAD / 128, 192 / 64), 256, 0, stream>>>(H3, w4b, b4, Fb, 192, 192);

  fnorm_bf<<<M_PAD / 4, 256, 0, stream>>>(Fb, fnorm);
  pnorm_bf<<<PPAD / 4, 256, 0, stream>>>(plb, pnl);
  pnorm_f32<<<P_ / 4, 256, 0, stream>>>(proto_g, png);

  dist_img_mfma<<<dim3(PPAD / 128, B_), 256, 0, stream>>>(Fb, plb, fnorm, pnl, actl);
  dist_cls<<<(B_ * P_) / 256, 256, 0, stream>>>(Fb, proto_g, fnorm, png, actg);

  final_k<<<B_, 256, 0, stream>>>(actg, actl, last_wg, last_w, out);
}

// Round 3
// 207.482 us; speedup vs baseline: 4.4233x; 1.1661x over previous
//
#include <hip/hip_runtime.h>
#include <cstdint>
#include <cstddef>

#define B_     128
#define N_TOK  196
#define D_IN   768
#define K_SEL  144
#define P_     2000
#define PPAD   2048
#define C_     192
#define NC_    200
#define RPB    160            // padded rows per batch: 1 cls + 144 sel + 15 pad
#define M_PAD  (B_ * RPB)     // 20480
#define EPS_   1e-4f
#define KC_    250            // k-chunk for final_partial (4000 = 16*250)
#define BT_    16             // batch-tile for final_partial (128 = 8*16)

typedef __bf16 bf16;
typedef bf16 bf16x8 __attribute__((ext_vector_type(8)));
typedef bf16 bf16x4 __attribute__((ext_vector_type(4)));
typedef float f32x4 __attribute__((ext_vector_type(4)));

#define MFMA(a, b, c) __builtin_amdgcn_mfma_f32_16x16x32_bf16(a, b, c, 0, 0, 0)

__device__ __forceinline__ void gload_lds16(const void* g, void* l) {
  __builtin_amdgcn_global_load_lds(
      (const __attribute__((address_space(1))) unsigned int*)g,
      (__attribute__((address_space(3))) unsigned int*)l, 16, 0, 0);
}

// ---------------------------------------------------------------------------
// top-K (stable, lower-index-wins like lax.top_k) -> absolute x_tokens row per
// padded slot: slot 0 = cls, 1..144 = sorted selected, 145..159 = -1.
// ---------------------------------------------------------------------------
__global__ __launch_bounds__(256) void topk_rowidx(const float* __restrict__ attn,
                                                   int* __restrict__ rowidx) {
  __shared__ float av[N_TOK];
  __shared__ int   flag[N_TOK];
  int b = blockIdx.x, t = threadIdx.x;
  if (t < N_TOK) av[t] = attn[b * N_TOK + t];
  __syncthreads();
  if (t < N_TOK) {
    float v = av[t];
    int rank = 0;
    for (int j = 0; j < N_TOK; ++j) {
      float u = av[j];
      rank += (u > v || (u == v && j < t)) ? 1 : 0;
    }
    flag[t] = (rank < K_SEL) ? 1 : 0;
  }
  __syncthreads();
  if (t == 0) rowidx[b * RPB] = b * (N_TOK + 1);
  if (t < RPB - (K_SEL + 1)) rowidx[b * RPB + K_SEL + 1 + t] = -1;
  if (t < N_TOK && flag[t]) {
    int pos = 0;
    for (int j = 0; j < t; ++j) pos += flag[j];
    rowidx[b * RPB + 1 + pos] = b * (N_TOK + 1) + 1 + t;
  }
}

// ---------------------------------------------------------------------------
// f32 -> bf16 convert with zero-padding of the tail (n_valid..n_total).
// ---------------------------------------------------------------------------
__global__ __launch_bounds__(256) void cvt_pad(const float* __restrict__ s,
                                               bf16* __restrict__ d,
                                               int n_valid, int n_total) {
  int i = (blockIdx.x * 256 + threadIdx.x) * 4;
  if (i >= n_total) return;
  bf16x4 o;
#pragma unroll
  for (int j = 0; j < 4; ++j)
    o[j] = (i + j < n_valid) ? (bf16)s[i + j] : (bf16)0.f;
  *reinterpret_cast<bf16x4*>(d + i) = o;
}

// ---------------------------------------------------------------------------
// Gather selected token rows from x_tokens, convert f32 -> bf16.
// ---------------------------------------------------------------------------
__global__ __launch_bounds__(192) void gather_cvt(const float* __restrict__ x,
                                                  const int* __restrict__ rowidx,
                                                  bf16* __restrict__ A0) {
  int row = blockIdx.x;
  int src = rowidx[row];
  int t = threadIdx.x;
  bf16x4 o;
  if (src >= 0) {
    float4 v = *reinterpret_cast<const float4*>(x + (size_t)src * D_IN + t * 4);
    o[0] = (bf16)v.x; o[1] = (bf16)v.y; o[2] = (bf16)v.z; o[3] = (bf16)v.w;
  } else {
    o[0] = (bf16)0.f; o[1] = (bf16)0.f; o[2] = (bf16)0.f; o[3] = (bf16)0.f;
  }
  *reinterpret_cast<bf16x4*>(A0 + (size_t)row * D_IN + t * 4) = o;
}

// ---------------------------------------------------------------------------
// bf16 MFMA GEMM: out[M_PAD,N] = act(A[M_PAD,Kd] @ W[N,Kd]^T + bias), bf16 out.
// BM=128 BN=64 BK=64, 4 waves (2x2), wave tile 64x32 (4x2 frags of 16x16x32).
// LDS XOR-swizzled (16B granule) with pre-swizzled global source (rule #21).
// ---------------------------------------------------------------------------
template <int ACT>
__global__ __launch_bounds__(256, 2) void gemm_bf16(
    const bf16* __restrict__ A, const bf16* __restrict__ W,
    const float* __restrict__ bias, bf16* __restrict__ out, int N, int Kd) {
  __shared__ __align__(16) bf16 As[128 * 64];
  __shared__ __align__(16) bf16 Bs[64 * 64];
  const int bm = blockIdx.x * 128, bn = blockIdx.y * 64;
  const int tid = threadIdx.x;
  const int lane = tid & 63, wid = tid >> 6;
  const int wm = (wid >> 1) * 64, wn = (wid & 1) * 32;
  const int l15 = lane & 15, lhi = lane >> 4;
  f32x4 acc[4][2] = {};
  for (int k0 = 0; k0 < Kd; k0 += 64) {
#pragma unroll
    for (int i = 0; i < 4; ++i) {
      int o = i * 256 + tid;
      int r = o >> 3, cb = o & 7;
      int gc = (cb ^ (r & 7)) * 8;
      gload_lds16(A + (size_t)(bm + r) * Kd + k0 + gc, (char*)As + o * 16);
    }
#pragma unroll
    for (int i = 0; i < 2; ++i) {
      int o = i * 256 + tid;
      int r = o >> 3, cb = o & 7;
      int gc = (cb ^ (r & 7)) * 8;
      gload_lds16(W + (size_t)(bn + r) * Kd + k0 + gc, (char*)Bs + o * 16);
    }
    __syncthreads();
#pragma unroll
    for (int kk = 0; kk < 2; ++kk) {
      bf16x8 bfr[2];
#pragma unroll
      for (int nf = 0; nf < 2; ++nf) {
        int rr = wn + nf * 16 + l15;
        int c = kk * 4 + lhi;
        bfr[nf] = *reinterpret_cast<const bf16x8*>(
            (const char*)Bs + (rr * 8 + (c ^ (rr & 7))) * 16);
      }
#pragma unroll
      for (int mf = 0; mf < 4; ++mf) {
        int rr = wm + mf * 16 + l15;
        int c = kk * 4 + lhi;
        bf16x8 afr = *reinterpret_cast<const bf16x8*>(
            (const char*)As + (rr * 8 + (c ^ (rr & 7))) * 16);
#pragma unroll
        for (int nf = 0; nf < 2; ++nf)
          acc[mf][nf] = MFMA(afr, bfr[nf], acc[mf][nf]);
      }
    }
    __syncthreads();
  }
#pragma unroll
  for (int mf = 0; mf < 4; ++mf)
#pragma unroll
    for (int nf = 0; nf < 2; ++nf) {
      int col = bn + wn + nf * 16 + l15;
      float bv = bias[col];
#pragma unroll
      for (int q = 0; q < 4; ++q) {
        int row = bm + wm + mf * 16 + lhi * 4 + q;
        float v = acc[mf][nf][q] + bv;
        v = (ACT == 0) ? fmaxf(v, 0.f) : 1.f / (1.f + expf(-v));
        out[(size_t)row * N + col] = (bf16)v;
      }
    }
}

// ---------------------------------------------------------------------------
// norms
// ---------------------------------------------------------------------------
__global__ __launch_bounds__(256) void fnorm_bf(const bf16* __restrict__ F,
                                                float* __restrict__ fnorm) {
  int m = blockIdx.x * 4 + (threadIdx.x >> 6);
  int lane = threadIdx.x & 63;
  const bf16* f = F + (size_t)m * C_;
  float s = 0.f;
#pragma unroll
  for (int k = 0; k < 3; ++k) {
    float v = (float)f[lane + k * 64];
    s += v * v;
  }
  for (int o = 32; o > 0; o >>= 1) s += __shfl_down(s, o, 64);
  if (lane == 0) fnorm[m] = s;
}

__global__ __launch_bounds__(256) void pnorm_bf(const bf16* __restrict__ P,
                                                float* __restrict__ pn) {
  int m = blockIdx.x * 4 + (threadIdx.x >> 6);
  int lane = threadIdx.x & 63;
  const bf16* f = P + (size_t)m * C_;
  float s = 0.f;
#pragma unroll
  for (int k = 0; k < 3; ++k) {
    float v = (float)f[lane + k * 64];
    s += v * v;
  }
  for (int o = 32; o > 0; o >>= 1) s += __shfl_down(s, o, 64);
  if (lane == 0) pn[m] = s;
}

__global__ __launch_bounds__(256) void pnorm_f32(const float* __restrict__ P,
                                                 float* __restrict__ pn) {
  int m = blockIdx.x * 4 + (threadIdx.x >> 6);
  int lane = threadIdx.x & 63;
  const float* f = P + (size_t)m * C_;
  float s = 0.f;
#pragma unroll
  for (int k = 0; k < 3; ++k) {
    float v = f[lane + k * 64];
    s += v * v;
  }
  for (int o = 32; o > 0; o >>= 1) s += __shfl_down(s, o, 64);
  if (lane == 0) pn[m] = s;
}

// ---------------------------------------------------------------------------
// Per-batch distance + min-over-tokens + log activation, bf16 MFMA.
// ---------------------------------------------------------------------------
__global__ __launch_bounds__(256, 2) void dist_img_mfma(
    const bf16* __restrict__ F, const bf16* __restrict__ P,
    const float* __restrict__ fnorm, const float* __restrict__ pnorm,
    float* __restrict__ act_l) {
  __shared__ __align__(16) bf16 Fs[160 * 64];
  __shared__ __align__(16) bf16 Ps[128 * 64];
  __shared__ float fn[RPB];
  const int b = blockIdx.y;
  const int p0 = blockIdx.x * 128;
  const int tid = threadIdx.x;
  const int lane = tid & 63, wid = tid >> 6;
  const int wn = wid * 32;
  const int l15 = lane & 15, lhi = lane >> 4;
  if (tid < RPB) fn[tid] = fnorm[b * RPB + tid];
  f32x4 acc[10][2] = {};
  for (int k0 = 0; k0 < C_; k0 += 64) {
#pragma unroll
    for (int i = 0; i < 5; ++i) {
      int o = i * 256 + tid;
      int r = o >> 3, cb = o & 7;
      int gc = (cb ^ (r & 7)) * 8;
      gload_lds16(F + (size_t)(b * RPB + r) * C_ + k0 + gc, (char*)Fs + o * 16);
    }
#pragma unroll
    for (int i = 0; i < 4; ++i) {
      int o = i * 256 + tid;
      int r = o >> 3, cb = o & 7;
      int gc = (cb ^ (r & 7)) * 8;
      gload_lds16(P + (size_t)(p0 + r) * C_ + k0 + gc, (char*)Ps + o * 16);
    }
    __syncthreads();
#pragma unroll
    for (int kk = 0; kk < 2; ++kk) {
      bf16x8 bfr[2];
#pragma unroll
      for (int nf = 0; nf < 2; ++nf) {
        int rr = wn + nf * 16 + l15;
        int c = kk * 4 + lhi;
        bfr[nf] = *reinterpret_cast<const bf16x8*>(
            (const char*)Ps + (rr * 8 + (c ^ (rr & 7))) * 16);
      }
#pragma unroll
      for (int mf = 0; mf < 10; ++mf) {
        int rr = mf * 16 + l15;
        int c = kk * 4 + lhi;
        bf16x8 afr = *reinterpret_cast<const bf16x8*>(
            (const char*)Fs + (rr * 8 + (c ^ (rr & 7))) * 16);
#pragma unroll
        for (int nf = 0; nf < 2; ++nf)
          acc[mf][nf] = MFMA(afr, bfr[nf], acc[mf][nf]);
      }
    }
    __syncthreads();
  }
#pragma unroll
  for (int nf = 0; nf < 2; ++nf) {
    float mn = 3.4e38f;
#pragma unroll
    for (int mf = 0; mf < 10; ++mf)
#pragma unroll
      for (int q = 0; q < 4; ++q) {
        int row = mf * 16 + lhi * 4 + q;
        float e = fn[row] - 2.f * acc[mf][nf][q];
        if (row >= 1 && row <= K_SEL) mn = fminf(mn, e);
      }
    mn = fminf(mn, __shfl_xor(mn, 16, 64));
    mn = fminf(mn, __shfl_xor(mn, 32, 64));
    int p = p0 + wn + nf * 16 + l15;
    if (lhi == 0 && p < P_) {
      float d = fmaxf(mn + pnorm[p], 0.f);
      act_l[(size_t)b * P_ + p] = logf((d + 1.f) / (d + EPS_));
    }
  }
}

// ---------------------------------------------------------------------------
// CLS distances vs proto_global (f32 protos, bf16 cls feature rows).
// ---------------------------------------------------------------------------
__global__ __launch_bounds__(256) void dist_cls(
    const bf16* __restrict__ F, const float* __restrict__ proto,
    const float* __restrict__ fnorm, const float* __restrict__ pnorm,
    float* __restrict__ act_g) {
  int i = blockIdx.x * 256 + threadIdx.x;  // 128*2000 threads exactly
  int b = i / P_, p = i - b * P_;
  const bf16* f = F + (size_t)(b * RPB) * C_;
  const float* pr = proto + (size_t)p * C_;
  float dot = 0.f;
  for (int k = 0; k < C_; k += 8) {
    bf16x8 fv = *reinterpret_cast<const bf16x8*>(f + k);
    float4 p0 = *reinterpret_cast<const float4*>(pr + k);
    float4 p1 = *reinterpret_cast<const float4*>(pr + k + 4);
    dot += (float)fv[0] * p0.x + (float)fv[1] * p0.y + (float)fv[2] * p0.z +
           (float)fv[3] * p0.w + (float)fv[4] * p1.x + (float)fv[5] * p1.y +
           (float)fv[6] * p1.z + (float)fv[7] * p1.w;
  }
  float d = fmaxf(fnorm[b * RPB] - 2.f * dot + pnorm[p], 0.f);
  act_g[i] = logf((d + 1.f) / (d + EPS_));
}

// ---------------------------------------------------------------------------
// Final stage, 3 kernels:
// prep_wt: wT[k][c] = k<2000 ? 0.3*lwg[c][k] : 0.7*lw[c][k-2000]   (4000x200)
// final_partial: part[kc][b][c] = sum_{k in chunk kc} act[b][k]*wT[k][c]
// final_reduce:  out[b][c] = sum_kc part[kc][b][c]
// ---------------------------------------------------------------------------
__global__ __launch_bounds__(256) void prep_wt(const float* __restrict__ lwg,
                                               const float* __restrict__ lw,
                                               float* __restrict__ wT) {
  int i = blockIdx.x * 256 + threadIdx.x;
  if (i >= 4000 * NC_) return;
  int k = i / NC_, c = i - k * NC_;
  float v = (k < 2000) ? 0.3f * lwg[(size_t)c * 2000 + k]
                       : 0.7f * lw[(size_t)c * 2000 + (k - 2000)];
  wT[i] = v;
}

__global__ __launch_bounds__(256) void final_partial(
    const float* __restrict__ actg, const float* __restrict__ actl,
    const float* __restrict__ wT, float* __restrict__ part) {
  __shared__ __align__(16) float sa[KC_ * 20];  // [k][b], stride 20 (16B-align ok)
  const int bt = blockIdx.x;   // 0..7
  const int kc = blockIdx.y;   // 0..15
  const int t = threadIdx.x;
  const int b0 = bt * BT_;
  const int kg0 = kc * KC_;
  for (int i = t; i < KC_ * BT_; i += 256) {
    int b = i / KC_;
    int k = i - b * KC_;
    int kg = kg0 + k;
    float v = (kg < 2000) ? actg[(size_t)(b0 + b) * P_ + kg]
                          : actl[(size_t)(b0 + b) * P_ + (kg - 2000)];
    sa[k * 20 + b] = v;
  }
  __syncthreads();
  const int c = t;
  float acc[BT_] = {};
#pragma unroll 2
  for (int k = 0; k < KC_; ++k) {
    float w = (c < NC_) ? wT[(size_t)(kg0 + k) * NC_ + c] : 0.f;
    const float4* s4 = reinterpret_cast<const float4*>(&sa[k * 20]);
#pragma unroll
    for (int b4 = 0; b4 < 4; ++b4) {
      float4 a = s4[b4];
      acc[b4 * 4 + 0] += w * a.x;
      acc[b4 * 4 + 1] += w * a.y;
      acc[b4 * 4 + 2] += w * a.z;
      acc[b4 * 4 + 3] += w * a.w;
    }
  }
  if (c < NC_) {
#pragma unroll
    for (int b = 0; b < BT_; ++b)
      part[((size_t)kc * B_ + b0 + b) * NC_ + c] = acc[b];
  }
}

__global__ __launch_bounds__(256) void final_reduce(const float* __restrict__ part,
                                                    float* __restrict__ out) {
  int i = blockIdx.x * 256 + threadIdx.x;
  if (i >= B_ * NC_) return;
  float s = 0.f;
#pragma unroll
  for (int kc = 0; kc < 16; ++kc) s += part[(size_t)kc * (B_ * NC_) + i];
  out[i] = s;
}

// ---------------------------------------------------------------------------
extern "C" void kernel_launch(void* const* d_in, const int* in_sizes, int n_in,
                              void* d_out, int out_size, void* d_ws, size_t ws_size,
                              hipStream_t stream) {
  const float* x_tokens = (const float*)d_in[0];
  const float* attn     = (const float*)d_in[1];
  const float* w1 = (const float*)d_in[2];
  const float* b1 = (const float*)d_in[3];
  const float* w2 = (const float*)d_in[4];
  const float* b2 = (const float*)d_in[5];
  const float* w3 = (const float*)d_in[6];
  const float* b3 = (const float*)d_in[7];
  const float* w4 = (const float*)d_in[8];
  const float* b4 = (const float*)d_in[9];
  const float* proto_l = (const float*)d_in[10];
  const float* proto_g = (const float*)d_in[11];
  const float* last_w  = (const float*)d_in[12];
  const float* last_wg = (const float*)d_in[13];
  float* out = (float*)d_out;

  char* wsb = (char*)d_ws;
  auto alloc = [&](size_t bytes) {
    char* p = wsb;
    wsb += (bytes + 255) & ~(size_t)255;
    return p;
  };
  bf16* X = (bf16*)alloc((size_t)M_PAD * D_IN * sizeof(bf16));   // 31.5 MB
  bf16* Y = (bf16*)alloc((size_t)M_PAD * 384 * sizeof(bf16));    // 15.7 MB
  bf16* w1b = (bf16*)alloc((size_t)384 * 768 * sizeof(bf16));
  bf16* w2b = (bf16*)alloc((size_t)384 * 384 * sizeof(bf16));
  bf16* w3b = (bf16*)alloc((size_t)192 * 384 * sizeof(bf16));
  bf16* w4b = (bf16*)alloc((size_t)192 * 192 * sizeof(bf16));
  bf16* plb = (bf16*)alloc((size_t)PPAD * C_ * sizeof(bf16));
  int*   rowidx = (int*)  alloc((size_t)M_PAD * sizeof(int));
  float* fnorm  = (float*)alloc((size_t)M_PAD * sizeof(float));
  float* pnl    = (float*)alloc((size_t)PPAD * sizeof(float));
  float* png    = (float*)alloc((size_t)P_ * sizeof(float));
  float* actg   = (float*)alloc((size_t)B_ * P_ * sizeof(float));
  float* actl   = (float*)alloc((size_t)B_ * P_ * sizeof(float));

  bf16* A0 = X;        // [M_PAD][768]
  bf16* H1 = Y;        // [M_PAD][384]
  bf16* H2 = X;        // [M_PAD][384]
  bf16* H3 = Y;        // [M_PAD][192]
  bf16* Fb = X;        // [M_PAD][192]

  // final-stage scratch aliases Y (dead after gemm4 reads H3):
  float* wT   = (float*)Y;                       // 4000*200*4 = 3.2 MB
  float* part = (float*)((char*)Y + 4 * 1024 * 1024);  // 16*128*200*4 = 1.6 MB

  topk_rowidx<<<B_, 256, 0, stream>>>(attn, rowidx);

  cvt_pad<<<(384 * 768 / 4 + 255) / 256, 256, 0, stream>>>(w1, w1b, 384 * 768, 384 * 768);
  cvt_pad<<<(384 * 384 / 4 + 255) / 256, 256, 0, stream>>>(w2, w2b, 384 * 384, 384 * 384);
  cvt_pad<<<(192 * 384 / 4 + 255) / 256, 256, 0, stream>>>(w3, w3b, 192 * 384, 192 * 384);
  cvt_pad<<<(192 * 192 / 4 + 255) / 256, 256, 0, stream>>>(w4, w4b, 192 * 192, 192 * 192);
  cvt_pad<<<(PPAD * C_ / 4 + 255) / 256, 256, 0, stream>>>(proto_l, plb, P_ * C_, PPAD * C_);

  gather_cvt<<<M_PAD, 192, 0, stream>>>(x_tokens, rowidx, A0);

  gemm_bf16<0><<<dim3(M_PAD / 128, 384 / 64), 256, 0, stream>>>(A0, w1b, b1, H1, 384, 768);
  gemm_bf16<0><<<dim3(M_PAD / 128, 384 / 64), 256, 0, stream>>>(H1, w2b, b2, H2, 384, 384);
  gemm_bf16<0><<<dim3(M_PAD / 128, 192 / 64), 256, 0, stream>>>(H2, w3b, b3, H3, 192, 384);
  gemm_bf16<1><<<dim3(M_PAD / 128, 192 / 64), 256, 0, stream>>>(H3, w4b, b4, Fb, 192, 192);

  // Y (H3) is dead from here; wT/part alias it.
  prep_wt<<<(4000 * NC_ + 255) / 256, 256, 0, stream>>>(last_wg, last_w, wT);

  fnorm_bf<<<M_PAD / 4, 256, 0, stream>>>(Fb, fnorm);
  pnorm_bf<<<PPAD / 4, 256, 0, stream>>>(plb, pnl);
  pnorm_f32<<<P_ / 4, 256, 0, stream>>>(proto_g, png);

  dist_img_mfma<<<dim3(PPAD / 128, B_), 256, 0, stream>>>(Fb, plb, fnorm, pnl, actl);
  dist_cls<<<(B_ * P_) / 256, 256, 0, stream>>>(Fb, proto_g, fnorm, png, actg);

  final_partial<<<dim3(B_ / BT_, 4000 / KC_), 256, 0, stream>>>(actg, actl, wT, part);
  final_reduce<<<(B_ * NC_ + 255) / 256, 256, 0, stream>>>(part, out);
}

// Round 4
// 156.088 us; speedup vs baseline: 5.8798x; 1.3293x over previous
//
#include <hip/hip_runtime.h>
#include <cstdint>
#include <cstddef>

#define B_     128
#define N_TOK  196
#define D_IN   768
#define K_SEL  144
#define P_     2000
#define PPAD   2048
#define C_     192
#define NC_    200
#define RPB    160            // padded rows per batch: 1 cls + 144 sel + 15 pad
#define M_PAD  (B_ * RPB)     // 20480
#define EPS_   1e-4f
#define KC_    100            // k-chunk for final_partial (4000 = 40*100)
#define NKC    40
#define BT_    8              // batch-tile for final_partial (128 = 16*8)

typedef __bf16 bf16;
typedef bf16 bf16x8 __attribute__((ext_vector_type(8)));
typedef bf16 bf16x4 __attribute__((ext_vector_type(4)));
typedef float f32x4 __attribute__((ext_vector_type(4)));

#define MFMA(a, b, c) __builtin_amdgcn_mfma_f32_16x16x32_bf16(a, b, c, 0, 0, 0)

__device__ __forceinline__ void gload_lds16(const void* g, void* l) {
  __builtin_amdgcn_global_load_lds(
      (const __attribute__((address_space(1))) unsigned int*)g,
      (__attribute__((address_space(3))) unsigned int*)l, 16, 0, 0);
}

// ---------------------------------------------------------------------------
// top-K (stable, lower-index-wins like lax.top_k) -> absolute x_tokens row per
// padded slot: slot 0 = cls, 1..144 = sorted selected, 145..159 = -1.
// ---------------------------------------------------------------------------
__global__ __launch_bounds__(256) void topk_rowidx(const float* __restrict__ attn,
                                                   int* __restrict__ rowidx) {
  __shared__ float av[N_TOK];
  __shared__ int   flag[N_TOK];
  int b = blockIdx.x, t = threadIdx.x;
  if (t < N_TOK) av[t] = attn[b * N_TOK + t];
  __syncthreads();
  if (t < N_TOK) {
    float v = av[t];
    int rank = 0;
    for (int j = 0; j < N_TOK; ++j) {
      float u = av[j];
      rank += (u > v || (u == v && j < t)) ? 1 : 0;
    }
    flag[t] = (rank < K_SEL) ? 1 : 0;
  }
  __syncthreads();
  if (t == 0) rowidx[b * RPB] = b * (N_TOK + 1);
  if (t < RPB - (K_SEL + 1)) rowidx[b * RPB + K_SEL + 1 + t] = -1;
  if (t < N_TOK && flag[t]) {
    int pos = 0;
    for (int j = 0; j < t; ++j) pos += flag[j];
    rowidx[b * RPB + 1 + pos] = b * (N_TOK + 1) + 1 + t;
  }
}

// ---------------------------------------------------------------------------
// Fused f32 -> bf16 convert for all 4 weights + proto_local (zero-padded tail).
// Segment sizes in float4 units; all coalesced.
// ---------------------------------------------------------------------------
#define SEG1 73728     // 384*768/4
#define SEG2 36864     // 384*384/4
#define SEG3 18432     // 192*384/4
#define SEG4 9216      // 192*192/4
#define SEG5 98304     // PPAD*C_/4
#define CVT_TOT (SEG1 + SEG2 + SEG3 + SEG4 + SEG5)  // 236544

__global__ __launch_bounds__(256) void cvt_all(
    const float* __restrict__ w1, const float* __restrict__ w2,
    const float* __restrict__ w3, const float* __restrict__ w4,
    const float* __restrict__ pl,
    bf16* __restrict__ w1b, bf16* __restrict__ w2b,
    bf16* __restrict__ w3b, bf16* __restrict__ w4b,
    bf16* __restrict__ plb) {
  int i4 = blockIdx.x * 256 + threadIdx.x;
  if (i4 >= CVT_TOT) return;
  const float* s; bf16* d; int nv; int base;
  if (i4 < SEG1)                       { s = w1; d = w1b; nv = 384 * 768; base = i4; }
  else if (i4 < SEG1 + SEG2)           { s = w2; d = w2b; nv = 384 * 384; base = i4 - SEG1; }
  else if (i4 < SEG1 + SEG2 + SEG3)    { s = w3; d = w3b; nv = 192 * 384; base = i4 - (SEG1 + SEG2); }
  else if (i4 < SEG1 + SEG2 + SEG3 + SEG4) { s = w4; d = w4b; nv = 192 * 192; base = i4 - (SEG1 + SEG2 + SEG3); }
  else                                 { s = pl; d = plb; nv = P_ * C_; base = i4 - (SEG1 + SEG2 + SEG3 + SEG4); }
  int i = base * 4;
  bf16x4 o;
#pragma unroll
  for (int j = 0; j < 4; ++j)
    o[j] = (i + j < nv) ? (bf16)s[i + j] : (bf16)0.f;
  *reinterpret_cast<bf16x4*>(d + i) = o;
}

// ---------------------------------------------------------------------------
// Gather selected token rows from x_tokens, convert f32 -> bf16.
// ---------------------------------------------------------------------------
__global__ __launch_bounds__(192) void gather_cvt(const float* __restrict__ x,
                                                  const int* __restrict__ rowidx,
                                                  bf16* __restrict__ A0) {
  int row = blockIdx.x;
  int src = rowidx[row];
  int t = threadIdx.x;
  bf16x4 o;
  if (src >= 0) {
    float4 v = *reinterpret_cast<const float4*>(x + (size_t)src * D_IN + t * 4);
    o[0] = (bf16)v.x; o[1] = (bf16)v.y; o[2] = (bf16)v.z; o[3] = (bf16)v.w;
  } else {
    o[0] = (bf16)0.f; o[1] = (bf16)0.f; o[2] = (bf16)0.f; o[3] = (bf16)0.f;
  }
  *reinterpret_cast<bf16x4*>(A0 + (size_t)row * D_IN + t * 4) = o;
}

// ---------------------------------------------------------------------------
// bf16 MFMA GEMM: out[M_PAD,N] = act(A[M_PAD,Kd] @ W[N,Kd]^T + bias), bf16 out.
// BM=128 BN=64 BK=64, 4 waves (2x2), wave tile 64x32 (4x2 frags of 16x16x32).
// LDS XOR-swizzled (16B granule) with pre-swizzled global source (rule #21).
// ---------------------------------------------------------------------------
template <int ACT>
__global__ __launch_bounds__(256, 2) void gemm_bf16(
    const bf16* __restrict__ A, const bf16* __restrict__ W,
    const float* __restrict__ bias, bf16* __restrict__ out, int N, int Kd) {
  __shared__ __align__(16) bf16 As[128 * 64];
  __shared__ __align__(16) bf16 Bs[64 * 64];
  const int bm = blockIdx.x * 128, bn = blockIdx.y * 64;
  const int tid = threadIdx.x;
  const int lane = tid & 63, wid = tid >> 6;
  const int wm = (wid >> 1) * 64, wn = (wid & 1) * 32;
  const int l15 = lane & 15, lhi = lane >> 4;
  f32x4 acc[4][2] = {};
  for (int k0 = 0; k0 < Kd; k0 += 64) {
#pragma unroll
    for (int i = 0; i < 4; ++i) {
      int o = i * 256 + tid;
      int r = o >> 3, cb = o & 7;
      int gc = (cb ^ (r & 7)) * 8;
      gload_lds16(A + (size_t)(bm + r) * Kd + k0 + gc, (char*)As + o * 16);
    }
#pragma unroll
    for (int i = 0; i < 2; ++i) {
      int o = i * 256 + tid;
      int r = o >> 3, cb = o & 7;
      int gc = (cb ^ (r & 7)) * 8;
      gload_lds16(W + (size_t)(bn + r) * Kd + k0 + gc, (char*)Bs + o * 16);
    }
    __syncthreads();
#pragma unroll
    for (int kk = 0; kk < 2; ++kk) {
      bf16x8 bfr[2];
#pragma unroll
      for (int nf = 0; nf < 2; ++nf) {
        int rr = wn + nf * 16 + l15;
        int c = kk * 4 + lhi;
        bfr[nf] = *reinterpret_cast<const bf16x8*>(
            (const char*)Bs + (rr * 8 + (c ^ (rr & 7))) * 16);
      }
#pragma unroll
      for (int mf = 0; mf < 4; ++mf) {
        int rr = wm + mf * 16 + l15;
        int c = kk * 4 + lhi;
        bf16x8 afr = *reinterpret_cast<const bf16x8*>(
            (const char*)As + (rr * 8 + (c ^ (rr & 7))) * 16);
#pragma unroll
        for (int nf = 0; nf < 2; ++nf)
          acc[mf][nf] = MFMA(afr, bfr[nf], acc[mf][nf]);
      }
    }
    __syncthreads();
  }
#pragma unroll
  for (int mf = 0; mf < 4; ++mf)
#pragma unroll
    for (int nf = 0; nf < 2; ++nf) {
      int col = bn + wn + nf * 16 + l15;
      float bv = bias[col];
#pragma unroll
      for (int q = 0; q < 4; ++q) {
        int row = bm + wm + mf * 16 + lhi * 4 + q;
        float v = acc[mf][nf][q] + bv;
        v = (ACT == 0) ? fmaxf(v, 0.f) : 1.f / (1.f + expf(-v));
        out[(size_t)row * N + col] = (bf16)v;
      }
    }
}

// ---------------------------------------------------------------------------
// Fused norms: rows 0..20479 = Fb (bf16) -> fnorm; 20480..22527 = plb (bf16)
// -> pnl; 22528..24527 = proto_g (f32) -> png.
// ---------------------------------------------------------------------------
__global__ __launch_bounds__(256) void norms_all(
    const bf16* __restrict__ F, const bf16* __restrict__ plb,
    const float* __restrict__ pg, float* __restrict__ fnorm,
    float* __restrict__ pnl, float* __restrict__ png) {
  int m = blockIdx.x * 4 + (threadIdx.x >> 6);
  int lane = threadIdx.x & 63;
  float s = 0.f;
  if (m < M_PAD) {
    const bf16* f = F + (size_t)m * C_;
#pragma unroll
    for (int k = 0; k < 3; ++k) { float v = (float)f[lane + k * 64]; s += v * v; }
  } else if (m < M_PAD + PPAD) {
    const bf16* f = plb + (size_t)(m - M_PAD) * C_;
#pragma unroll
    for (int k = 0; k < 3; ++k) { float v = (float)f[lane + k * 64]; s += v * v; }
  } else if (m < M_PAD + PPAD + P_) {
    const float* f = pg + (size_t)(m - M_PAD - PPAD) * C_;
#pragma unroll
    for (int k = 0; k < 3; ++k) { float v = f[lane + k * 64]; s += v * v; }
  } else return;
  for (int o = 32; o > 0; o >>= 1) s += __shfl_down(s, o, 64);
  if (lane == 0) {
    if (m < M_PAD) fnorm[m] = s;
    else if (m < M_PAD + PPAD) pnl[m - M_PAD] = s;
    else png[m - M_PAD - PPAD] = s;
  }
}

// ---------------------------------------------------------------------------
// Per-batch distance + min-over-tokens + log activation, bf16 MFMA.
// ---------------------------------------------------------------------------
__global__ __launch_bounds__(256, 2) void dist_img_mfma(
    const bf16* __restrict__ F, const bf16* __restrict__ P,
    const float* __restrict__ fnorm, const float* __restrict__ pnorm,
    float* __restrict__ act_l) {
  __shared__ __align__(16) bf16 Fs[160 * 64];
  __shared__ __align__(16) bf16 Ps[128 * 64];
  __shared__ float fn[RPB];
  const int b = blockIdx.y;
  const int p0 = blockIdx.x * 128;
  const int tid = threadIdx.x;
  const int lane = tid & 63, wid = tid >> 6;
  const int wn = wid * 32;
  const int l15 = lane & 15, lhi = lane >> 4;
  if (tid < RPB) fn[tid] = fnorm[b * RPB + tid];
  f32x4 acc[10][2] = {};
  for (int k0 = 0; k0 < C_; k0 += 64) {
#pragma unroll
    for (int i = 0; i < 5; ++i) {
      int o = i * 256 + tid;
      int r = o >> 3, cb = o & 7;
      int gc = (cb ^ (r & 7)) * 8;
      gload_lds16(F + (size_t)(b * RPB + r) * C_ + k0 + gc, (char*)Fs + o * 16);
    }
#pragma unroll
    for (int i = 0; i < 4; ++i) {
      int o = i * 256 + tid;
      int r = o >> 3, cb = o & 7;
      int gc = (cb ^ (r & 7)) * 8;
      gload_lds16(P + (size_t)(p0 + r) * C_ + k0 + gc, (char*)Ps + o * 16);
    }
    __syncthreads();
#pragma unroll
    for (int kk = 0; kk < 2; ++kk) {
      bf16x8 bfr[2];
#pragma unroll
      for (int nf = 0; nf < 2; ++nf) {
        int rr = wn + nf * 16 + l15;
        int c = kk * 4 + lhi;
        bfr[nf] = *reinterpret_cast<const bf16x8*>(
            (const char*)Ps + (rr * 8 + (c ^ (rr & 7))) * 16);
      }
#pragma unroll
      for (int mf = 0; mf < 10; ++mf) {
        int rr = mf * 16 + l15;
        int c = kk * 4 + lhi;
        bf16x8 afr = *reinterpret_cast<const bf16x8*>(
            (const char*)Fs + (rr * 8 + (c ^ (rr & 7))) * 16);
#pragma unroll
        for (int nf = 0; nf < 2; ++nf)
          acc[mf][nf] = MFMA(afr, bfr[nf], acc[mf][nf]);
      }
    }
    __syncthreads();
  }
#pragma unroll
  for (int nf = 0; nf < 2; ++nf) {
    float mn = 3.4e38f;
#pragma unroll
    for (int mf = 0; mf < 10; ++mf)
#pragma unroll
      for (int q = 0; q < 4; ++q) {
        int row = mf * 16 + lhi * 4 + q;
        float e = fn[row] - 2.f * acc[mf][nf][q];
        if (row >= 1 && row <= K_SEL) mn = fminf(mn, e);
      }
    mn = fminf(mn, __shfl_xor(mn, 16, 64));
    mn = fminf(mn, __shfl_xor(mn, 32, 64));
    int p = p0 + wn + nf * 16 + l15;
    if (lhi == 0 && p < P_) {
      float d = fmaxf(mn + pnorm[p], 0.f);
      act_l[(size_t)b * P_ + p] = logf((d + 1.f) / (d + EPS_));
    }
  }
}

// ---------------------------------------------------------------------------
// CLS distances vs proto_global (f32 protos, bf16 cls feature rows).
// ---------------------------------------------------------------------------
__global__ __launch_bounds__(256) void dist_cls(
    const bf16* __restrict__ F, const float* __restrict__ proto,
    const float* __restrict__ fnorm, const float* __restrict__ pnorm,
    float* __restrict__ act_g) {
  int i = blockIdx.x * 256 + threadIdx.x;  // 128*2000 threads exactly
  int b = i / P_, p = i - b * P_;
  const bf16* f = F + (size_t)(b * RPB) * C_;
  const float* pr = proto + (size_t)p * C_;
  float dot = 0.f;
  for (int k = 0; k < C_; k += 8) {
    bf16x8 fv = *reinterpret_cast<const bf16x8*>(f + k);
    float4 p0 = *reinterpret_cast<const float4*>(pr + k);
    float4 p1 = *reinterpret_cast<const float4*>(pr + k + 4);
    dot += (float)fv[0] * p0.x + (float)fv[1] * p0.y + (float)fv[2] * p0.z +
           (float)fv[3] * p0.w + (float)fv[4] * p1.x + (float)fv[5] * p1.y +
           (float)fv[6] * p1.z + (float)fv[7] * p1.w;
  }
  float d = fmaxf(fnorm[b * RPB] - 2.f * dot + pnorm[p], 0.f);
  act_g[i] = logf((d + 1.f) / (d + EPS_));
}

// ---------------------------------------------------------------------------
// Final stage:
// prep_wt: wT2[c][k] = k<2000 ? 0.3*lwg[c][k] : 0.7*lw[c][k-2000]  (200x4000,
//          c-major so final_partial reads contiguous k-runs as float4).
// final_partial: part[kc][b][c] = sum_{k in chunk} act[b][k] * wT2[c][k]
// final_reduce:  out[b][c] = sum_kc part[kc][b][c]
// ---------------------------------------------------------------------------
__global__ __launch_bounds__(256) void prep_wt(const float* __restrict__ lwg,
                                               const float* __restrict__ lw,
                                               float* __restrict__ wT2) {
  int i = blockIdx.x * 256 + threadIdx.x;
  if (i >= NC_ * 4000) return;
  int c = i / 4000, k = i - c * 4000;
  float v = (k < 2000) ? 0.3f * lwg[(size_t)c * 2000 + k]
                       : 0.7f * lw[(size_t)c * 2000 + (k - 2000)];
  wT2[i] = v;
}

__global__ __launch_bounds__(256) void final_partial(
    const float* __restrict__ actg, const float* __restrict__ actl,
    const float* __restrict__ wT2, float* __restrict__ part) {
  __shared__ __align__(16) float sa[KC_][BT_];
  const int kc = blockIdx.x;   // 0..39
  const int bt = blockIdx.y;   // 0..15
  const int t = threadIdx.x;
  const int b0 = bt * BT_;
  const int kg0 = kc * KC_;
  const float* act = (kg0 < 2000) ? actg : actl;
  const int koff = (kg0 < 2000) ? kg0 : kg0 - 2000;
  for (int i = t; i < KC_ * BT_; i += 256) {
    int b = i / KC_;
    int k = i - b * KC_;
    sa[k][b] = act[(size_t)(b0 + b) * P_ + koff + k];
  }
  __syncthreads();
  const int c = t;
  if (c >= NC_) return;
  float acc[BT_] = {};
  const float4* w4p = reinterpret_cast<const float4*>(wT2 + (size_t)c * 4000 + kg0);
#pragma unroll 5
  for (int k4 = 0; k4 < KC_ / 4; ++k4) {
    float4 w4 = w4p[k4];
    float wv[4] = {w4.x, w4.y, w4.z, w4.w};
#pragma unroll
    for (int j = 0; j < 4; ++j) {
      float w = wv[j];
      const float4* s4 = reinterpret_cast<const float4*>(&sa[k4 * 4 + j][0]);
      float4 a0 = s4[0], a1 = s4[1];
      acc[0] += w * a0.x; acc[1] += w * a0.y; acc[2] += w * a0.z; acc[3] += w * a0.w;
      acc[4] += w * a1.x; acc[5] += w * a1.y; acc[6] += w * a1.z; acc[7] += w * a1.w;
    }
  }
#pragma unroll
  for (int b = 0; b < BT_; ++b)
    part[((size_t)kc * B_ + b0 + b) * NC_ + c] = acc[b];
}

__global__ __launch_bounds__(256) void final_reduce(const float* __restrict__ part,
                                                    float* __restrict__ out) {
  int i = blockIdx.x * 256 + threadIdx.x;
  if (i >= B_ * NC_) return;
  float s = 0.f;
#pragma unroll 8
  for (int kc = 0; kc < NKC; ++kc) s += part[(size_t)kc * (B_ * NC_) + i];
  out[i] = s;
}

// ---------------------------------------------------------------------------
extern "C" void kernel_launch(void* const* d_in, const int* in_sizes, int n_in,
                              void* d_out, int out_size, void* d_ws, size_t ws_size,
                              hipStream_t stream) {
  const float* x_tokens = (const float*)d_in[0];
  const float* attn     = (const float*)d_in[1];
  const float* w1 = (const float*)d_in[2];
  const float* b1 = (const float*)d_in[3];
  const float* w2 = (const float*)d_in[4];
  const float* b2 = (const float*)d_in[5];
  const float* w3 = (const float*)d_in[6];
  const float* b3 = (const float*)d_in[7];
  const float* w4 = (const float*)d_in[8];
  const float* b4 = (const float*)d_in[9];
  const float* proto_l = (const float*)d_in[10];
  const float* proto_g = (const float*)d_in[11];
  const float* last_w  = (const float*)d_in[12];
  const float* last_wg = (const float*)d_in[13];
  float* out = (float*)d_out;

  char* wsb = (char*)d_ws;
  auto alloc = [&](size_t bytes) {
    char* p = wsb;
    wsb += (bytes + 255) & ~(size_t)255;
    return p;
  };
  bf16* X = (bf16*)alloc((size_t)M_PAD * D_IN * sizeof(bf16));   // 31.5 MB
  bf16* Y = (bf16*)alloc((size_t)M_PAD * 384 * sizeof(bf16));    // 15.7 MB
  bf16* w1b = (bf16*)alloc((size_t)384 * 768 * sizeof(bf16));
  bf16* w2b = (bf16*)alloc((size_t)384 * 384 * sizeof(bf16));
  bf16* w3b = (bf16*)alloc((size_t)192 * 384 * sizeof(bf16));
  bf16* w4b = (bf16*)alloc((size_t)192 * 192 * sizeof(bf16));
  bf16* plb = (bf16*)alloc((size_t)PPAD * C_ * sizeof(bf16));
  int*   rowidx = (int*)  alloc((size_t)M_PAD * sizeof(int));
  float* fnorm  = (float*)alloc((size_t)M_PAD * sizeof(float));
  float* pnl    = (float*)alloc((size_t)PPAD * sizeof(float));
  float* png    = (float*)alloc((size_t)P_ * sizeof(float));
  float* actg   = (float*)alloc((size_t)B_ * P_ * sizeof(float));
  float* actl   = (float*)alloc((size_t)B_ * P_ * sizeof(float));

  bf16* A0 = X;        // [M_PAD][768]
  bf16* H1 = Y;        // [M_PAD][384]
  bf16* H2 = X;        // [M_PAD][384]
  bf16* H3 = Y;        // [M_PAD][192]
  bf16* Fb = X;        // [M_PAD][192]

  // final-stage scratch aliases Y (dead after gemm4 reads H3):
  float* wT2  = (float*)Y;                              // 200*4000*4 = 3.2 MB
  float* part = (float*)((char*)Y + 4 * 1024 * 1024);   // 40*128*200*4 = 4.1 MB

  topk_rowidx<<<B_, 256, 0, stream>>>(attn, rowidx);

  cvt_all<<<(CVT_TOT + 255) / 256, 256, 0, stream>>>(w1, w2, w3, w4, proto_l,
                                                     w1b, w2b, w3b, w4b, plb);

  gather_cvt<<<M_PAD, 192, 0, stream>>>(x_tokens, rowidx, A0);

  gemm_bf16<0><<<dim3(M_PAD / 128, 384 / 64), 256, 0, stream>>>(A0, w1b, b1, H1, 384, 768);
  gemm_bf16<0><<<dim3(M_PAD / 128, 384 / 64), 256, 0, stream>>>(H1, w2b, b2, H2, 384, 384);
  gemm_bf16<0><<<dim3(M_PAD / 128, 192 / 64), 256, 0, stream>>>(H2, w3b, b3, H3, 192, 384);
  gemm_bf16<1><<<dim3(M_PAD / 128, 192 / 64), 256, 0, stream>>>(H3, w4b, b4, Fb, 192, 192);

  // Y (H3) is dead from here; wT2/part alias it.
  prep_wt<<<(NC_ * 4000 + 255) / 256, 256, 0, stream>>>(last_wg, last_w, wT2);

  norms_all<<<(M_PAD + PPAD + P_) / 4, 256, 0, stream>>>(Fb, plb, proto_g,
                                                         fnorm, pnl, png);

  dist_img_mfma<<<dim3(PPAD / 128, B_), 256, 0, stream>>>(Fb, plb, fnorm, pnl, actl);
  dist_cls<<<(B_ * P_) / 256, 256, 0, stream>>>(Fb, proto_g, fnorm, png, actg);

  final_partial<<<dim3(NKC, B_ / BT_), 256, 0, stream>>>(actg, actl, wT2, part);
  final_reduce<<<(B_ * NC_ + 255) / 256, 256, 0, stream>>>(part, out);
}

// Round 5
// 155.551 us; speedup vs baseline: 5.9001x; 1.0035x over previous
//
#include <hip/hip_runtime.h>
#include <cstdint>
#include <cstddef>

#define B_     128
#define N_TOK  196
#define D_IN   768
#define K_SEL  144
#define P_     2000
#define PPAD   2048
#define C_     192
#define NC_    200
#define RPB    160            // padded rows per batch: 1 cls + 144 sel + 15 pad
#define M_PAD  (B_ * RPB)     // 20480
#define EPS_   1e-4f
#define KC_    100            // k-chunk for final_partial (4000 = 40*100)
#define NKC    40
#define BT_    8              // batch-tile for final_partial (128 = 16*8)

typedef __bf16 bf16;
typedef bf16 bf16x8 __attribute__((ext_vector_type(8)));
typedef bf16 bf16x4 __attribute__((ext_vector_type(4)));
typedef float f32x4 __attribute__((ext_vector_type(4)));

#define MFMA(a, b, c) __builtin_amdgcn_mfma_f32_16x16x32_bf16(a, b, c, 0, 0, 0)

__device__ __forceinline__ void gload_lds16(const void* g, void* l) {
  __builtin_amdgcn_global_load_lds(
      (const __attribute__((address_space(1))) unsigned int*)g,
      (__attribute__((address_space(3))) unsigned int*)l, 16, 0, 0);
}

// ---------------------------------------------------------------------------
// top-K (stable, lower-index-wins like lax.top_k) -> absolute x_tokens row per
// padded slot: slot 0 = cls, 1..144 = sorted selected, 145..159 = -1.
// ---------------------------------------------------------------------------
__global__ __launch_bounds__(256) void topk_rowidx(const float* __restrict__ attn,
                                                   int* __restrict__ rowidx) {
  __shared__ float av[N_TOK];
  __shared__ int   flag[N_TOK];
  int b = blockIdx.x, t = threadIdx.x;
  if (t < N_TOK) av[t] = attn[b * N_TOK + t];
  __syncthreads();
  if (t < N_TOK) {
    float v = av[t];
    int rank = 0;
    for (int j = 0; j < N_TOK; ++j) {
      float u = av[j];
      rank += (u > v || (u == v && j < t)) ? 1 : 0;
    }
    flag[t] = (rank < K_SEL) ? 1 : 0;
  }
  __syncthreads();
  if (t == 0) rowidx[b * RPB] = b * (N_TOK + 1);
  if (t < RPB - (K_SEL + 1)) rowidx[b * RPB + K_SEL + 1 + t] = -1;
  if (t < N_TOK && flag[t]) {
    int pos = 0;
    for (int j = 0; j < t; ++j) pos += flag[j];
    rowidx[b * RPB + 1 + pos] = b * (N_TOK + 1) + 1 + t;
  }
}

// ---------------------------------------------------------------------------
// Fused f32 -> bf16 convert for all 4 weights + proto_local (zero-padded tail).
// ---------------------------------------------------------------------------
#define SEG1 73728     // 384*768/4
#define SEG2 36864     // 384*384/4
#define SEG3 18432     // 192*384/4
#define SEG4 9216      // 192*192/4
#define SEG5 98304     // PPAD*C_/4
#define CVT_TOT (SEG1 + SEG2 + SEG3 + SEG4 + SEG5)  // 236544

__global__ __launch_bounds__(256) void cvt_all(
    const float* __restrict__ w1, const float* __restrict__ w2,
    const float* __restrict__ w3, const float* __restrict__ w4,
    const float* __restrict__ pl,
    bf16* __restrict__ w1b, bf16* __restrict__ w2b,
    bf16* __restrict__ w3b, bf16* __restrict__ w4b,
    bf16* __restrict__ plb) {
  int i4 = blockIdx.x * 256 + threadIdx.x;
  if (i4 >= CVT_TOT) return;
  const float* s; bf16* d; int nv; int base;
  if (i4 < SEG1)                       { s = w1; d = w1b; nv = 384 * 768; base = i4; }
  else if (i4 < SEG1 + SEG2)           { s = w2; d = w2b; nv = 384 * 384; base = i4 - SEG1; }
  else if (i4 < SEG1 + SEG2 + SEG3)    { s = w3; d = w3b; nv = 192 * 384; base = i4 - (SEG1 + SEG2); }
  else if (i4 < SEG1 + SEG2 + SEG3 + SEG4) { s = w4; d = w4b; nv = 192 * 192; base = i4 - (SEG1 + SEG2 + SEG3); }
  else                                 { s = pl; d = plb; nv = P_ * C_; base = i4 - (SEG1 + SEG2 + SEG3 + SEG4); }
  int i = base * 4;
  bf16x4 o;
#pragma unroll
  for (int j = 0; j < 4; ++j)
    o[j] = (i + j < nv) ? (bf16)s[i + j] : (bf16)0.f;
  *reinterpret_cast<bf16x4*>(d + i) = o;
}

// ---------------------------------------------------------------------------
// Gather selected token rows from x_tokens, convert f32 -> bf16.
// ---------------------------------------------------------------------------
__global__ __launch_bounds__(192) void gather_cvt(const float* __restrict__ x,
                                                  const int* __restrict__ rowidx,
                                                  bf16* __restrict__ A0) {
  int row = blockIdx.x;
  int src = rowidx[row];
  int t = threadIdx.x;
  bf16x4 o;
  if (src >= 0) {
    float4 v = *reinterpret_cast<const float4*>(x + (size_t)src * D_IN + t * 4);
    o[0] = (bf16)v.x; o[1] = (bf16)v.y; o[2] = (bf16)v.z; o[3] = (bf16)v.w;
  } else {
    o[0] = (bf16)0.f; o[1] = (bf16)0.f; o[2] = (bf16)0.f; o[3] = (bf16)0.f;
  }
  *reinterpret_cast<bf16x4*>(A0 + (size_t)row * D_IN + t * 4) = o;
}

// ---------------------------------------------------------------------------
// bf16 MFMA GEMM: out[M_PAD,N] = act(A[M_PAD,Kd] @ W[N,Kd]^T + bias), bf16 out.
// BM=128, BN templated (128 for N=384 layers, 64 for N=192 layers), BK=64.
// 4 waves (2x2): wave tile 64 x (BN/2), frags 4 x (BN/32) of 16x16x32.
// LDS XOR-swizzled (16B granule) with pre-swizzled global source (rule #21).
// ---------------------------------------------------------------------------
template <int ACT, int BN>
__global__ __launch_bounds__(256, 2) void gemm_bf16(
    const bf16* __restrict__ A, const bf16* __restrict__ W,
    const float* __restrict__ bias, bf16* __restrict__ out, int N, int Kd) {
  constexpr int NF = BN / 32;            // N-frags per wave
  __shared__ __align__(16) bf16 As[128 * 64];
  __shared__ __align__(16) bf16 Bs[BN * 64];
  const int bm = blockIdx.x * 128, bn = blockIdx.y * BN;
  const int tid = threadIdx.x;
  const int lane = tid & 63, wid = tid >> 6;
  const int wm = (wid >> 1) * 64, wn = (wid & 1) * (BN / 2);
  const int l15 = lane & 15, lhi = lane >> 4;
  f32x4 acc[4][NF] = {};
  for (int k0 = 0; k0 < Kd; k0 += 64) {
#pragma unroll
    for (int i = 0; i < 4; ++i) {
      int o = i * 256 + tid;
      int r = o >> 3, cb = o & 7;
      int gc = (cb ^ (r & 7)) * 8;
      gload_lds16(A + (size_t)(bm + r) * Kd + k0 + gc, (char*)As + o * 16);
    }
#pragma unroll
    for (int i = 0; i < NF; ++i) {
      int o = i * 256 + tid;
      int r = o >> 3, cb = o & 7;
      int gc = (cb ^ (r & 7)) * 8;
      gload_lds16(W + (size_t)(bn + r) * Kd + k0 + gc, (char*)Bs + o * 16);
    }
    __syncthreads();
#pragma unroll
    for (int kk = 0; kk < 2; ++kk) {
      bf16x8 bfr[NF];
#pragma unroll
      for (int nf = 0; nf < NF; ++nf) {
        int rr = wn + nf * 16 + l15;
        int c = kk * 4 + lhi;
        bfr[nf] = *reinterpret_cast<const bf16x8*>(
            (const char*)Bs + (rr * 8 + (c ^ (rr & 7))) * 16);
      }
#pragma unroll
      for (int mf = 0; mf < 4; ++mf) {
        int rr = wm + mf * 16 + l15;
        int c = kk * 4 + lhi;
        bf16x8 afr = *reinterpret_cast<const bf16x8*>(
            (const char*)As + (rr * 8 + (c ^ (rr & 7))) * 16);
#pragma unroll
        for (int nf = 0; nf < NF; ++nf)
          acc[mf][nf] = MFMA(afr, bfr[nf], acc[mf][nf]);
      }
    }
    __syncthreads();
  }
#pragma unroll
  for (int mf = 0; mf < 4; ++mf)
#pragma unroll
    for (int nf = 0; nf < NF; ++nf) {
      int col = bn + wn + nf * 16 + l15;
      float bv = bias[col];
#pragma unroll
      for (int q = 0; q < 4; ++q) {
        int row = bm + wm + mf * 16 + lhi * 4 + q;
        float v = acc[mf][nf][q] + bv;
        v = (ACT == 0) ? fmaxf(v, 0.f) : 1.f / (1.f + expf(-v));
        out[(size_t)row * N + col] = (bf16)v;
      }
    }
}

// ---------------------------------------------------------------------------
// Fused norms: rows 0..20479 = Fb (bf16) -> fnorm; 20480..22527 = plb (bf16)
// -> pnl; 22528..24527 = proto_g (f32) -> png.
// ---------------------------------------------------------------------------
__global__ __launch_bounds__(256) void norms_all(
    const bf16* __restrict__ F, const bf16* __restrict__ plb,
    const float* __restrict__ pg, float* __restrict__ fnorm,
    float* __restrict__ pnl, float* __restrict__ png) {
  int m = blockIdx.x * 4 + (threadIdx.x >> 6);
  int lane = threadIdx.x & 63;
  float s = 0.f;
  if (m < M_PAD) {
    const bf16* f = F + (size_t)m * C_;
#pragma unroll
    for (int k = 0; k < 3; ++k) { float v = (float)f[lane + k * 64]; s += v * v; }
  } else if (m < M_PAD + PPAD) {
    const bf16* f = plb + (size_t)(m - M_PAD) * C_;
#pragma unroll
    for (int k = 0; k < 3; ++k) { float v = (float)f[lane + k * 64]; s += v * v; }
  } else if (m < M_PAD + PPAD + P_) {
    const float* f = pg + (size_t)(m - M_PAD - PPAD) * C_;
#pragma unroll
    for (int k = 0; k < 3; ++k) { float v = f[lane + k * 64]; s += v * v; }
  } else return;
  for (int o = 32; o > 0; o >>= 1) s += __shfl_down(s, o, 64);
  if (lane == 0) {
    if (m < M_PAD) fnorm[m] = s;
    else if (m < M_PAD + PPAD) pnl[m - M_PAD] = s;
    else png[m - M_PAD - PPAD] = s;
  }
}

// ---------------------------------------------------------------------------
// Per-batch distance + min-over-tokens + log activation, bf16 MFMA.
// ---------------------------------------------------------------------------
__global__ __launch_bounds__(256, 2) void dist_img_mfma(
    const bf16* __restrict__ F, const bf16* __restrict__ P,
    const float* __restrict__ fnorm, const float* __restrict__ pnorm,
    float* __restrict__ act_l) {
  __shared__ __align__(16) bf16 Fs[160 * 64];
  __shared__ __align__(16) bf16 Ps[128 * 64];
  __shared__ float fn[RPB];
  const int b = blockIdx.y;
  const int p0 = blockIdx.x * 128;
  const int tid = threadIdx.x;
  const int lane = tid & 63, wid = tid >> 6;
  const int wn = wid * 32;
  const int l15 = lane & 15, lhi = lane >> 4;
  if (tid < RPB) fn[tid] = fnorm[b * RPB + tid];
  f32x4 acc[10][2] = {};
  for (int k0 = 0; k0 < C_; k0 += 64) {
#pragma unroll
    for (int i = 0; i < 5; ++i) {
      int o = i * 256 + tid;
      int r = o >> 3, cb = o & 7;
      int gc = (cb ^ (r & 7)) * 8;
      gload_lds16(F + (size_t)(b * RPB + r) * C_ + k0 + gc, (char*)Fs + o * 16);
    }
#pragma unroll
    for (int i = 0; i < 4; ++i) {
      int o = i * 256 + tid;
      int r = o >> 3, cb = o & 7;
      int gc = (cb ^ (r & 7)) * 8;
      gload_lds16(P + (size_t)(p0 + r) * C_ + k0 + gc, (char*)Ps + o * 16);
    }
    __syncthreads();
#pragma unroll
    for (int kk = 0; kk < 2; ++kk) {
      bf16x8 bfr[2];
#pragma unroll
      for (int nf = 0; nf < 2; ++nf) {
        int rr = wn + nf * 16 + l15;
        int c = kk * 4 + lhi;
        bfr[nf] = *reinterpret_cast<const bf16x8*>(
            (const char*)Ps + (rr * 8 + (c ^ (rr & 7))) * 16);
      }
#pragma unroll
      for (int mf = 0; mf < 10; ++mf) {
        int rr = mf * 16 + l15;
        int c = kk * 4 + lhi;
        bf16x8 afr = *reinterpret_cast<const bf16x8*>(
            (const char*)Fs + (rr * 8 + (c ^ (rr & 7))) * 16);
#pragma unroll
        for (int nf = 0; nf < 2; ++nf)
          acc[mf][nf] = MFMA(afr, bfr[nf], acc[mf][nf]);
      }
    }
    __syncthreads();
  }
#pragma unroll
  for (int nf = 0; nf < 2; ++nf) {
    float mn = 3.4e38f;
#pragma unroll
    for (int mf = 0; mf < 10; ++mf)
#pragma unroll
      for (int q = 0; q < 4; ++q) {
        int row = mf * 16 + lhi * 4 + q;
        float e = fn[row] - 2.f * acc[mf][nf][q];
        if (row >= 1 && row <= K_SEL) mn = fminf(mn, e);
      }
    mn = fminf(mn, __shfl_xor(mn, 16, 64));
    mn = fminf(mn, __shfl_xor(mn, 32, 64));
    int p = p0 + wn + nf * 16 + l15;
    if (lhi == 0 && p < P_) {
      float d = fmaxf(mn + pnorm[p], 0.f);
      act_l[(size_t)b * P_ + p] = logf((d + 1.f) / (d + EPS_));
    }
  }
}

// ---------------------------------------------------------------------------
// CLS distances vs proto_global (f32 protos, bf16 cls feature rows).
// ---------------------------------------------------------------------------
__global__ __launch_bounds__(256) void dist_cls(
    const bf16* __restrict__ F, const float* __restrict__ proto,
    const float* __restrict__ fnorm, const float* __restrict__ pnorm,
    float* __restrict__ act_g) {
  int i = blockIdx.x * 256 + threadIdx.x;  // 128*2000 threads exactly
  int b = i / P_, p = i - b * P_;
  const bf16* f = F + (size_t)(b * RPB) * C_;
  const float* pr = proto + (size_t)p * C_;
  float dot = 0.f;
  for (int k = 0; k < C_; k += 8) {
    bf16x8 fv = *reinterpret_cast<const bf16x8*>(f + k);
    float4 p0 = *reinterpret_cast<const float4*>(pr + k);
    float4 p1 = *reinterpret_cast<const float4*>(pr + k + 4);
    dot += (float)fv[0] * p0.x + (float)fv[1] * p0.y + (float)fv[2] * p0.z +
           (float)fv[3] * p0.w + (float)fv[4] * p1.x + (float)fv[5] * p1.y +
           (float)fv[6] * p1.z + (float)fv[7] * p1.w;
  }
  float d = fmaxf(fnorm[b * RPB] - 2.f * dot + pnorm[p], 0.f);
  act_g[i] = logf((d + 1.f) / (d + EPS_));
}

// ---------------------------------------------------------------------------
// Final stage:
// prep_wt: wT2[c][k] = k<2000 ? 0.3*lwg[c][k] : 0.7*lw[c][k-2000]  (200x4000)
// final_partial: part[kc][b][c] = sum_{k in chunk} act[b][k] * wT2[c][k]
// final_reduce:  out[b][c] = sum_kc part[kc][b][c]
// ---------------------------------------------------------------------------
__global__ __launch_bounds__(256) void prep_wt(const float* __restrict__ lwg,
                                               const float* __restrict__ lw,
                                               float* __restrict__ wT2) {
  int i = blockIdx.x * 256 + threadIdx.x;
  if (i >= NC_ * 4000) return;
  int c = i / 4000, k = i - c * 4000;
  float v = (k < 2000) ? 0.3f * lwg[(size_t)c * 2000 + k]
                       : 0.7f * lw[(size_t)c * 2000 + (k - 2000)];
  wT2[i] = v;
}

__global__ __launch_bounds__(256) void final_partial(
    const float* __restrict__ actg, const float* __restrict__ actl,
    const float* __restrict__ wT2, float* __restrict__ part) {
  __shared__ __align__(16) float sa[KC_][BT_];
  const int kc = blockIdx.x;   // 0..39
  const int bt = blockIdx.y;   // 0..15
  const int t = threadIdx.x;
  const int b0 = bt * BT_;
  const int kg0 = kc * KC_;
  const float* act = (kg0 < 2000) ? actg : actl;
  const int koff = (kg0 < 2000) ? kg0 : kg0 - 2000;
  for (int i = t; i < KC_ * BT_; i += 256) {
    int b = i / KC_;
    int k = i - b * KC_;
    sa[k][b] = act[(size_t)(b0 + b) * P_ + koff + k];
  }
  __syncthreads();
  const int c = t;
  if (c >= NC_) return;
  float acc[BT_] = {};
  const float4* w4p = reinterpret_cast<const float4*>(wT2 + (size_t)c * 4000 + kg0);
#pragma unroll 5
  for (int k4 = 0; k4 < KC_ / 4; ++k4) {
    float4 w4 = w4p[k4];
    float wv[4] = {w4.x, w4.y, w4.z, w4.w};
#pragma unroll
    for (int j = 0; j < 4; ++j) {
      float w = wv[j];
      const float4* s4 = reinterpret_cast<const float4*>(&sa[k4 * 4 + j][0]);
      float4 a0 = s4[0], a1 = s4[1];
      acc[0] += w * a0.x; acc[1] += w * a0.y; acc[2] += w * a0.z; acc[3] += w * a0.w;
      acc[4] += w * a1.x; acc[5] += w * a1.y; acc[6] += w * a1.z; acc[7] += w * a1.w;
    }
  }
#pragma unroll
  for (int b = 0; b < BT_; ++b)
    part[((size_t)kc * B_ + b0 + b) * NC_ + c] = acc[b];
}

__global__ __launch_bounds__(256) void final_reduce(const float* __restrict__ part,
                                                    float* __restrict__ out) {
  int i = blockIdx.x * 256 + threadIdx.x;
  if (i >= B_ * NC_) return;
  float s = 0.f;
#pragma unroll 8
  for (int kc = 0; kc < NKC; ++kc) s += part[(size_t)kc * (B_ * NC_) + i];
  out[i] = s;
}

// ---------------------------------------------------------------------------
extern "C" void kernel_launch(void* const* d_in, const int* in_sizes, int n_in,
                              void* d_out, int out_size, void* d_ws, size_t ws_size,
                              hipStream_t stream) {
  const float* x_tokens = (const float*)d_in[0];
  const float* attn     = (const float*)d_in[1];
  const float* w1 = (const float*)d_in[2];
  const float* b1 = (const float*)d_in[3];
  const float* w2 = (const float*)d_in[4];
  const float* b2 = (const float*)d_in[5];
  const float* w3 = (const float*)d_in[6];
  const float* b3 = (const float*)d_in[7];
  const float* w4 = (const float*)d_in[8];
  const float* b4 = (const float*)d_in[9];
  const float* proto_l = (const float*)d_in[10];
  const float* proto_g = (const float*)d_in[11];
  const float* last_w  = (const float*)d_in[12];
  const float* last_wg = (const float*)d_in[13];
  float* out = (float*)d_out;

  char* wsb = (char*)d_ws;
  auto alloc = [&](size_t bytes) {
    char* p = wsb;
    wsb += (bytes + 255) & ~(size_t)255;
    return p;
  };
  bf16* X = (bf16*)alloc((size_t)M_PAD * D_IN * sizeof(bf16));   // 31.5 MB
  bf16* Y = (bf16*)alloc((size_t)M_PAD * 384 * sizeof(bf16));    // 15.7 MB
  bf16* w1b = (bf16*)alloc((size_t)384 * 768 * sizeof(bf16));
  bf16* w2b = (bf16*)alloc((size_t)384 * 384 * sizeof(bf16));
  bf16* w3b = (bf16*)alloc((size_t)192 * 384 * sizeof(bf16));
  bf16* w4b = (bf16*)alloc((size_t)192 * 192 * sizeof(bf16));
  bf16* plb = (bf16*)alloc((size_t)PPAD * C_ * sizeof(bf16));
  int*   rowidx = (int*)  alloc((size_t)M_PAD * sizeof(int));
  float* fnorm  = (float*)alloc((size_t)M_PAD * sizeof(float));
  float* pnl    = (float*)alloc((size_t)PPAD * sizeof(float));
  float* png    = (float*)alloc((size_t)P_ * sizeof(float));
  float* actg   = (float*)alloc((size_t)B_ * P_ * sizeof(float));
  float* actl   = (float*)alloc((size_t)B_ * P_ * sizeof(float));

  bf16* A0 = X;        // [M_PAD][768]
  bf16* H1 = Y;        // [M_PAD][384]
  bf16* H2 = X;        // [M_PAD][384]
  bf16* H3 = Y;        // [M_PAD][192]
  bf16* Fb = X;        // [M_PAD][192]

  // final-stage scratch aliases Y (dead after gemm4 reads H3):
  float* wT2  = (float*)Y;                              // 200*4000*4 = 3.2 MB
  float* part = (float*)((char*)Y + 4 * 1024 * 1024);   // 40*128*200*4 = 4.1 MB

  topk_rowidx<<<B_, 256, 0, stream>>>(attn, rowidx);

  cvt_all<<<(CVT_TOT + 255) / 256, 256, 0, stream>>>(w1, w2, w3, w4, proto_l,
                                                     w1b, w2b, w3b, w4b, plb);

  gather_cvt<<<M_PAD, 192, 0, stream>>>(x_tokens, rowidx, A0);

  gemm_bf16<0, 128><<<dim3(M_PAD / 128, 384 / 128), 256, 0, stream>>>(A0, w1b, b1, H1, 384, 768);
  gemm_bf16<0, 128><<<dim3(M_PAD / 128, 384 / 128), 256, 0, stream>>>(H1, w2b, b2, H2, 384, 384);
  gemm_bf16<0, 64><<<dim3(M_PAD / 128, 192 / 64), 256, 0, stream>>>(H2, w3b, b3, H3, 192, 384);
  gemm_bf16<1, 64><<<dim3(M_PAD / 128, 192 / 64), 256, 0, stream>>>(H3, w4b, b4, Fb, 192, 192);

  // Y (H3) is dead from here; wT2/part alias it.
  prep_wt<<<(NC_ * 4000 + 255) / 256, 256, 0, stream>>>(last_wg, last_w, wT2);

  norms_all<<<(M_PAD + PPAD + P_) / 4, 256, 0, stream>>>(Fb, plb, proto_g,
                                                         fnorm, pnl, png);

  dist_img_mfma<<<dim3(PPAD / 128, B_), 256, 0, stream>>>(Fb, plb, fnorm, pnl, actl);
  dist_cls<<<(B_ * P_) / 256, 256, 0, stream>>>(Fb, proto_g, fnorm, png, actg);

  final_partial<<<dim3(NKC, B_ / BT_), 256, 0, stream>>>(actg, actl, wT2, part);
  final_reduce<<<(B_ * NC_ + 255) / 256, 256, 0, stream>>>(part, out);
}